// Round 2
// baseline (1459.252 us; speedup 1.0000x reference)
//
#include <hip/hip_runtime.h>

#define QN 8
#define KN 1024
#define DN 256
#define NROWS 32768
#define IDX_BASE 8388608
#define LOSS_OFF 8650752
#define MARGIN 5e-3f
#define LCAP 6144u

// ws layout (float offsets)
#define WS_LOSS 0
#define WS_CNORM 8
#define WS_ANORM 8200
#define WS_RESID 40968       // float[8388608]
#define WS_RSPLIT 8429576    // bf16[8388608] -> 4194304 floats
#define WS_CSPLIT 12623880   // bf16[2097152] -> 1048576 floats

// dynamic LDS layout (bytes). 75 KB/block -> 2 blocks/CU (was 146.5 KB -> 1).
#define SM_AFULL 0           // 32768: A row-tile 64x256 bf16, 4 swizzled kk-slices
#define SM_BS    32768       // 16384: B slice 128x64 bf16, swizzled
#define SM_LCAND 49152       // 24576: uint[6144] id-only; lr[32][260] alias lives at smem+0 in update
#define SM_CHC   73728       // 512
#define SM_ANS   74240       // 256
#define SM_CNS   74496       // 512
#define SM_RMIN  75008       // 256
#define SM_LCNT  75264       // 16
#define SM_BYTES 75280

typedef __attribute__((ext_vector_type(8))) short short8v;
typedef __attribute__((ext_vector_type(4))) float f32x4;

static __device__ __forceinline__ unsigned short f2bf(float x) {
  unsigned int u = __float_as_uint(x);
  unsigned int r = (u + 0x7fffu + ((u >> 16) & 1u)) >> 16;
  return (unsigned short)r;
}

// numpy pairwise sum-of-squares over 256 floats (validated R1: absmax 0.0)
__device__ __forceinline__ float sum256_sq_np(const float* p) {
  float h[2];
#pragma unroll
  for (int half = 0; half < 2; ++half) {
    const float* a = p + half * 128;
    float r[8];
#pragma unroll
    for (int j = 0; j < 8; ++j) r[j] = __fmul_rn(a[j], a[j]);
    for (int i = 8; i < 128; i += 8) {
#pragma unroll
      for (int j = 0; j < 8; ++j) r[j] = __fadd_rn(r[j], __fmul_rn(a[i + j], a[i + j]));
    }
    h[half] = __fadd_rn(__fadd_rn(__fadd_rn(r[0], r[1]), __fadd_rn(r[2], r[3])),
                        __fadd_rn(__fadd_rn(r[4], r[5]), __fadd_rn(r[6], r[7])));
  }
  return __fadd_rn(h[0], h[1]);
}

__global__ void rvq_prep_norm(const float* __restrict__ cb, float* __restrict__ ws) {
  int g = blockIdx.x * blockDim.x + threadIdx.x;
  if (g < 8) ws[WS_LOSS + g] = 0.f;
  if (g < QN * KN) ws[WS_CNORM + g] = sum256_sq_np(cb + (size_t)g * DN);
}

__global__ void rvq_prep_cast(const float* __restrict__ cb, unsigned short* __restrict__ cs) {
  int gid = blockIdx.x * blockDim.x + threadIdx.x;
  const float4* c4 = (const float4*)cb;
  ushort4* s4 = (ushort4*)cs;
#pragma unroll
  for (int k = 0; k < 4; ++k) {
    int i = gid + k * 131072;
    float4 v = c4[i];
    s4[i] = make_ushort4(f2bf(v.x), f2bf(v.y), f2bf(v.z), f2bf(v.w));
  }
}

// q=0 init: Anorm(z) np-exact + RSPLIT=bf16(z)
__global__ void rvq_init_rows(const float* __restrict__ z, float* __restrict__ ws) {
  int t = blockIdx.x * blockDim.x + threadIdx.x;
  ws[WS_ANORM + t] = sum256_sq_np(z + (size_t)t * DN);
  const float4* z4 = (const float4*)z;
  ushort4* r4 = (ushort4*)(ws + WS_RSPLIT);
#pragma unroll 8
  for (int i = 0; i < 64; ++i) {
    int idx = i * 32768 + t;
    float4 v = z4[idx];
    r4[idx] = make_ushort4(f2bf(v.x), f2bf(v.y), f2bf(v.z), f2bf(v.w));
  }
}

// Fused per-q. 64-row tile, 512 blocks, 75 KB LDS -> 2 blocks/CU so one
// block's compute overlaps the other's barrier drains (R1 showed block-wide
// barrier serialization, not per-wave latency, is the cost).
// Candidate entries are id-only (4B): the stored-d prune in recheck is dropped
// (pure perf filter); exact recheck/tie-break/update numerics unchanged.
__global__ __launch_bounds__(512, 4) void rvq_fused(const float* __restrict__ z,
                                                    const float* __restrict__ cb,
                                                    float* __restrict__ ws,
                                                    float* __restrict__ out, int q) {
  extern __shared__ __align__(16) char smem[];
  uint4* Afull = (uint4*)(smem + SM_AFULL);            // 2048 uint4
  uint4* Bs4 = (uint4*)(smem + SM_BS);                 // 1024 uint4
  unsigned int* lcand = (unsigned int*)(smem + SM_LCAND);
  unsigned long long* chc = (unsigned long long*)(smem + SM_CHC);
  float* an_s = (float*)(smem + SM_ANS);
  float* cn_s = (float*)(smem + SM_CNS);
  unsigned int* rowmin = (unsigned int*)(smem + SM_RMIN);
  unsigned int* lcnt = (unsigned int*)(smem + SM_LCNT);
  const unsigned short* Ash = (const unsigned short*)Afull;
  const unsigned short* Bsh = (const unsigned short*)Bs4;

  const int tid = threadIdx.x;
  const int row0 = blockIdx.x * 64;
  const int wv = tid >> 6, lane = tid & 63, quad = lane >> 4, l15 = lane & 15;
  const int wr = wv >> 2, wc = wv & 3;
  const float* rsrc = (q == 0) ? z : (ws + WS_RESID);

  const uint4* Ag = (const uint4*)(ws + WS_RSPLIT);
  const uint4* Bg = (const uint4*)((const unsigned short*)(ws + WS_CSPLIT) + (size_t)q * KN * DN);

  if (tid < 64) {
    an_s[tid] = ws[WS_ANORM + row0 + tid];
    rowmin[tid] = 0x7f7fffffu;
    chc[tid] = ~0ull;
  }
  if (tid == 0) *lcnt = 0u;

  const int rb = tid >> 3, cch = tid & 7;   // rb in 0..63
  // Stage the full A row-tile once (swizzled per kk-slice); 1 uint4/thread/slice
#pragma unroll
  for (int kk2 = 0; kk2 < 4; ++kk2) {
    int r = rb;
    Afull[kk2 * 512 + r * 8 + (cch ^ (r & 7))] = Ag[(size_t)(row0 + r) * 32 + kk2 * 8 + cch];
  }

  f32x4 acc[2][2];
  uint4 pb[2];
#pragma unroll
  for (int p = 0; p < 2; ++p) pb[p] = Bg[(size_t)(p * 64 + rb) * 32 + cch];

  for (int it = 0; it < 32; ++it) {
    const int c = it >> 2, kk = it & 3;
    __syncthreads();                       // prev slice consumers done (covers init/A-stage)
#pragma unroll
    for (int p = 0; p < 2; ++p) {
      int r = p * 64 + rb;
      Bs4[r * 8 + (cch ^ (r & 7))] = pb[p];
    }
    if (kk == 0 && tid < 128) cn_s[tid] = ws[WS_CNORM + q * KN + c * 128 + tid];
    if (it + 1 < 32) {                     // prefetch next B slice
      int c2 = (it + 1) >> 2, kk2 = (it + 1) & 3;
#pragma unroll
      for (int p = 0; p < 2; ++p)
        pb[p] = Bg[(size_t)(c2 * 128 + p * 64 + rb) * 32 + kk2 * 8 + cch];
    }
    __syncthreads();

    if (kk == 0) {
#pragma unroll
      for (int i = 0; i < 2; ++i)
#pragma unroll
        for (int j = 0; j < 2; ++j) acc[i][j] = (f32x4){0.f, 0.f, 0.f, 0.f};
    }
#pragma unroll
    for (int s = 0; s < 2; ++s) {
      short8v a[2], b[2];
      int ph = (s * 4 + quad) ^ (l15 & 7);
#pragma unroll
      for (int i = 0; i < 2; ++i) {
        int ra = wr * 32 + i * 16 + l15;   // ra&7 == l15&7, matches stage swizzle
        a[i] = *(const short8v*)&Ash[kk * 4096 + ra * 64 + ph * 8];
      }
#pragma unroll
      for (int j = 0; j < 2; ++j) {
        int rc = wc * 32 + j * 16 + l15;
        b[j] = *(const short8v*)&Bsh[rc * 64 + ph * 8];
      }
#pragma unroll
      for (int i = 0; i < 2; ++i)
#pragma unroll
        for (int j = 0; j < 2; ++j)
          acc[i][j] = __builtin_amdgcn_mfma_f32_16x16x32_bf16(a[i], b[j], acc[i][j], 0, 0, 0);
    }

    if (kk == 3) {                         // chunk epilogue: min-merge + append
#pragma unroll
      for (int i = 0; i < 2; ++i) {
#pragma unroll
        for (int reg = 0; reg < 4; ++reg) {
          int rl = wr * 32 + i * 16 + quad * 4 + reg;
          float an = an_s[rl];
          float bd = 3.402823466e+38f;
#pragma unroll
          for (int j = 0; j < 2; ++j) {
            int cl = wc * 32 + j * 16 + l15;
            float d = __fadd_rn(__fadd_rn(an, -2.0f * acc[i][j][reg]), cn_s[cl]);
            bd = (d < bd) ? d : bd;
          }
#pragma unroll
          for (int m = 1; m <= 8; m <<= 1) {
            float od = __shfl_xor(bd, m, 64);
            bd = (od < bd) ? od : bd;
          }
          if (l15 == 0) atomicMin(&rowmin[rl], __float_as_uint(bd));
        }
      }
      __syncthreads();                     // running min (incl. this chunk) visible
#pragma unroll
      for (int i = 0; i < 2; ++i) {
#pragma unroll
        for (int reg = 0; reg < 4; ++reg) {
          int rl = wr * 32 + i * 16 + quad * 4 + reg;
          float an = an_s[rl];
          float thr = __uint_as_float(rowmin[rl]) + MARGIN;
#pragma unroll
          for (int j = 0; j < 2; ++j) {
            int cl = wc * 32 + j * 16 + l15;
            float d = __fadd_rn(__fadd_rn(an, -2.0f * acc[i][j][reg]), cn_s[cl]);
            if (d <= thr) {
              unsigned int p = atomicAdd(lcnt, 1u);
              if (p < LCAP)
                lcand[p] = ((unsigned)rl << 10) | (unsigned)(c * 128 + cl);
            }
          }
        }
      }
    }
  }
  __syncthreads();

  // ---- exact recheck (in-LDS) ----
  const float* cbq = cb + (size_t)q * KN * DN;
  const float* cnq = ws + WS_CNORM + q * KN;
  unsigned int n = *lcnt;
  if (n <= LCAP) {
    for (unsigned int e = tid; e < n; e += 512u) {
      unsigned int en = lcand[e];
      int rl = en >> 10, code = en & 1023;
      const float* r = rsrc + (size_t)(row0 + rl) * DN;
      const float* cc = cbq + (size_t)code * DN;
      float B = 0.f;
#pragma unroll 16
      for (int d = 0; d < DN; ++d) B = fmaf(r[d], cc[d], B);   // R1-exact serial chain
      float de = __fadd_rn(__fadd_rn(an_s[rl], -2.0f * B), cnq[code]);
      unsigned long long key = ((unsigned long long)__float_as_uint(de) << 32) | (unsigned)code;
      atomicMin(&chc[rl], key);
    }
  } else {
    // safety fallback: exhaustive exact argmin (correct; expected never at LCAP=6144/64rows)
    for (int e = tid; e < 64 * 1024; e += 512) {
      int rl = e >> 10, code = e & 1023;
      const float* r = rsrc + (size_t)(row0 + rl) * DN;
      const float* cc = cbq + (size_t)code * DN;
      float B = 0.f;
#pragma unroll 16
      for (int d = 0; d < DN; ++d) B = fmaf(r[d], cc[d], B);
      float de = __fadd_rn(__fadd_rn(an_s[rl], -2.0f * B), cnq[code]);
      unsigned long long key = ((unsigned long long)__float_as_uint(de) << 32) | (unsigned)code;
      atomicMin(&chc[rl], key);
    }
  }
  __syncthreads();

  // ---- np-exact update: 2 passes x 32 rows, 16 thr/row x 16 dims ----
  float (*lr)[260] = (float(*)[260])(smem + SM_AFULL);   // A/B dead; 33.3 KB alias below chc
  const bool last = (q == QN - 1);
  const int ur = tid >> 4, ud = tid & 15;                // ur in 0..31
  float lp = 0.f;
  for (int pass = 0; pass < 2; ++pass) {
    int rl = pass * 32 + ur;
    int row = row0 + rl;
    int idx = (int)(chc[rl] & 1023u);
    if (ud == 0) out[IDX_BASE + (size_t)q * NROWS + row] = (float)idx;

    const float4* r4 = (const float4*)(rsrc + (size_t)row * DN) + ud * 4;
    const float4* q4 = (const float4*)(cb + ((size_t)q * KN + idx) * DN) + ud * 4;
    float4 rnb[4];
#pragma unroll
    for (int t = 0; t < 4; ++t) {
      float4 r = r4[t], qv = q4[t];
      float tx = __fadd_rn(qv.x, -r.x), ty = __fadd_rn(qv.y, -r.y);
      float tz = __fadd_rn(qv.z, -r.z), tw = __fadd_rn(qv.w, -r.w);
      float sx = __fadd_rn(r.x, tx), sy = __fadd_rn(r.y, ty);
      float sz = __fadd_rn(r.z, tz), sw = __fadd_rn(r.w, tw);
      rnb[t] = make_float4(__fadd_rn(r.x, -sx), __fadd_rn(r.y, -sy),
                           __fadd_rn(r.z, -sz), __fadd_rn(r.w, -sw));
      lp = fmaf(tx, tx, lp); lp = fmaf(ty, ty, lp);
      lp = fmaf(tz, tz, lp); lp = fmaf(tw, tw, lp);
    }

    if (last) {
      const float4* z4 = (const float4*)(z + (size_t)row * DN) + ud * 4;
      float4* o4 = (float4*)(out + (size_t)row * DN) + ud * 4;
#pragma unroll
      for (int t = 0; t < 4; ++t) {
        float4 zv = z4[t];
        o4[t] = make_float4(__fadd_rn(zv.x, -rnb[t].x), __fadd_rn(zv.y, -rnb[t].y),
                            __fadd_rn(zv.z, -rnb[t].z), __fadd_rn(zv.w, -rnb[t].w));
      }
    } else {
      float4* rd = (float4*)(ws + WS_RESID + (size_t)row * DN) + ud * 4;
      ushort4* rs = (ushort4*)((unsigned short*)(ws + WS_RSPLIT) + (size_t)row * DN) + ud * 4;
#pragma unroll
      for (int t = 0; t < 4; ++t) {
        float4 v = rnb[t];
        rd[t] = v;
        rs[t] = make_ushort4(f2bf(v.x), f2bf(v.y), f2bf(v.z), f2bf(v.w));
        *(float4*)&lr[ur][ud * 16 + t * 4] = v;
      }
      __syncthreads();
      if (tid < 32) ws[WS_ANORM + row0 + pass * 32 + tid] = sum256_sq_np(&lr[tid][0]);
      __syncthreads();
    }
  }

#pragma unroll
  for (int off = 32; off > 0; off >>= 1) lp += __shfl_down(lp, off, 64);
  if (lane == 0) atomicAdd(ws + WS_LOSS + q, lp);
}

__global__ void rvq_fin(const float* __restrict__ ws, float* __restrict__ out) {
  if (blockIdx.x == 0 && threadIdx.x == 0) {
    float vq = 0.f;
    for (int q = 0; q < QN; ++q) {
      float m = ws[WS_LOSS + q] / 8388608.0f;
      float l = __fadd_rn(m, 0.25f * m);
      vq = __fadd_rn(vq, l);
    }
    out[LOSS_OFF] = vq;
  }
}

extern "C" void kernel_launch(void* const* d_in, const int* in_sizes, int n_in,
                              void* d_out, int out_size, void* d_ws, size_t ws_size,
                              hipStream_t stream) {
  const float* z = (const float*)d_in[0];
  const float* cb = (const float*)d_in[1];
  float* out = (float*)d_out;
  float* ws = (float*)d_ws;

  hipLaunchKernelGGL(rvq_prep_norm, dim3(32), dim3(256), 0, stream, cb, ws);
  hipLaunchKernelGGL(rvq_prep_cast, dim3(512), dim3(256), 0, stream, cb,
                     (unsigned short*)(ws + WS_CSPLIT));
  hipLaunchKernelGGL(rvq_init_rows, dim3(128), dim3(256), 0, stream, z, ws);

  for (int q = 0; q < QN; ++q)
    hipLaunchKernelGGL(rvq_fused, dim3(512), dim3(512), SM_BYTES, stream, z, cb, ws, out, q);

  hipLaunchKernelGGL(rvq_fin, dim3(1), dim3(64), 0, stream, ws, out);
}

// Round 3
// 1253.632 us; speedup vs baseline: 1.1640x; 1.1640x over previous
//
#include <hip/hip_runtime.h>

#define QN 8
#define KN 1024
#define DN 256
#define NROWS 32768
#define IDX_BASE 8388608
#define LOSS_OFF 8650752
#define MARGIN 5e-3f
#define LCAP 8192u

// ws layout (float offsets)
#define WS_LOSS 0
#define WS_CNORM 8
#define WS_ANORM 8200
#define WS_RESID 40968       // float[8388608]
#define WS_RSPLIT 8429576    // bf16[8388608] -> 4194304 floats
#define WS_CSPLIT 12623880   // bf16[2097152] -> 1048576 floats

// dynamic LDS layout (bytes). No B staging: B fragments come straight from
// global (L2-resident 512 KB codebook), killing 64 of 72 block barriers.
#define SM_AFULL 0           // 65536: A row-tile 128x256 bf16, 4 swizzled kk-slices
#define SM_CN    65536       // 4096: all 1024 codebook norms (staged once)
#define SM_LCAND 69632       // 65536: uint2[8192]
#define SM_CHC   135168      // 1024
#define SM_ANS   136192      // 512
#define SM_RMIN  136704      // 512
#define SM_LCNT  137216      // 16
#define SM_BYTES 137232

typedef __attribute__((ext_vector_type(8))) short short8v;
typedef __attribute__((ext_vector_type(4))) float f32x4;

static __device__ __forceinline__ unsigned short f2bf(float x) {
  unsigned int u = __float_as_uint(x);
  unsigned int r = (u + 0x7fffu + ((u >> 16) & 1u)) >> 16;
  return (unsigned short)r;
}

// numpy pairwise sum-of-squares over 256 floats (validated: absmax 0.0)
__device__ __forceinline__ float sum256_sq_np(const float* p) {
  float h[2];
#pragma unroll
  for (int half = 0; half < 2; ++half) {
    const float* a = p + half * 128;
    float r[8];
#pragma unroll
    for (int j = 0; j < 8; ++j) r[j] = __fmul_rn(a[j], a[j]);
    for (int i = 8; i < 128; i += 8) {
#pragma unroll
      for (int j = 0; j < 8; ++j) r[j] = __fadd_rn(r[j], __fmul_rn(a[i + j], a[i + j]));
    }
    h[half] = __fadd_rn(__fadd_rn(__fadd_rn(r[0], r[1]), __fadd_rn(r[2], r[3])),
                        __fadd_rn(__fadd_rn(r[4], r[5]), __fadd_rn(r[6], r[7])));
  }
  return __fadd_rn(h[0], h[1]);
}

__global__ void rvq_prep_norm(const float* __restrict__ cb, float* __restrict__ ws) {
  int g = blockIdx.x * blockDim.x + threadIdx.x;
  if (g < 8) ws[WS_LOSS + g] = 0.f;
  if (g < QN * KN) ws[WS_CNORM + g] = sum256_sq_np(cb + (size_t)g * DN);
}

__global__ void rvq_prep_cast(const float* __restrict__ cb, unsigned short* __restrict__ cs) {
  int gid = blockIdx.x * blockDim.x + threadIdx.x;
  const float4* c4 = (const float4*)cb;
  ushort4* s4 = (ushort4*)cs;
#pragma unroll
  for (int k = 0; k < 4; ++k) {
    int i = gid + k * 131072;
    float4 v = c4[i];
    s4[i] = make_ushort4(f2bf(v.x), f2bf(v.y), f2bf(v.z), f2bf(v.w));
  }
}

// q=0 init: Anorm(z) np-exact + RSPLIT=bf16(z)
__global__ void rvq_init_rows(const float* __restrict__ z, float* __restrict__ ws) {
  int t = blockIdx.x * blockDim.x + threadIdx.x;
  ws[WS_ANORM + t] = sum256_sq_np(z + (size_t)t * DN);
  const float4* z4 = (const float4*)z;
  ushort4* r4 = (ushort4*)(ws + WS_RSPLIT);
#pragma unroll 8
  for (int i = 0; i < 64; ++i) {
    int idx = i * 32768 + t;
    float4 v = z4[idx];
    r4[idx] = make_ushort4(f2bf(v.x), f2bf(v.y), f2bf(v.z), f2bf(v.w));
  }
}

// Fused per-q. R1 geometry (128 rows, 256 blocks, 512 thr) but barrier-light:
// B fragments loaded directly from global (no B-LDS, no per-slice barriers);
// 9 barriers in the screen instead of 72. Screen/recheck/update numerics
// identical to the validated R1 kernel (same MFMA order, margin, serial-fmaf
// recheck, u64 tie-break, np-exact update).
__global__ __launch_bounds__(512, 2) void rvq_fused(const float* __restrict__ z,
                                                    const float* __restrict__ cb,
                                                    float* __restrict__ ws,
                                                    float* __restrict__ out, int q) {
  extern __shared__ __align__(16) char smem[];
  uint4* Afull = (uint4*)(smem + SM_AFULL);            // 4096 uint4
  float* cn_all = (float*)(smem + SM_CN);              // 1024 norms
  uint2* lcand = (uint2*)(smem + SM_LCAND);
  unsigned long long* chc = (unsigned long long*)(smem + SM_CHC);
  float* an_s = (float*)(smem + SM_ANS);
  unsigned int* rowmin = (unsigned int*)(smem + SM_RMIN);
  unsigned int* lcnt = (unsigned int*)(smem + SM_LCNT);
  const unsigned short* Ash = (const unsigned short*)Afull;

  const int tid = threadIdx.x;
  const int row0 = blockIdx.x * 128;
  const int wv = tid >> 6, lane = tid & 63, quad = lane >> 4, l15 = lane & 15;
  const int wr = wv >> 2, wc = wv & 3;
  const float* rsrc = (q == 0) ? z : (ws + WS_RESID);

  const uint4* Ag = (const uint4*)(ws + WS_RSPLIT);
  const unsigned short* Bq = (const unsigned short*)(ws + WS_CSPLIT) + (size_t)q * KN * DN;
  // per-lane invariant fragment base: code (wc*32 + j*16 + l15), dim chunk quad
  const unsigned short* Bl = Bq + (size_t)((wc * 32 + l15) * 256 + quad * 8);

  if (tid < 128) {
    an_s[tid] = ws[WS_ANORM + row0 + tid];
    rowmin[tid] = 0x7f7fffffu;
    chc[tid] = ~0ull;
  }
  cn_all[tid] = ws[WS_CNORM + q * KN + tid];
  cn_all[tid + 512] = ws[WS_CNORM + q * KN + tid + 512];
  if (tid == 0) *lcnt = 0u;

  const int rb = tid >> 3, cch = tid & 7;   // rb in 0..63
  // Stage the full A row-tile once (swizzled per kk-slice)
#pragma unroll
  for (int kk2 = 0; kk2 < 4; ++kk2) {
#pragma unroll
    for (int p = 0; p < 2; ++p) {
      int r = p * 64 + rb;
      Afull[kk2 * 1024 + r * 8 + (cch ^ (r & 7))] = Ag[(size_t)(row0 + r) * 32 + kk2 * 8 + cch];
    }
  }
  __syncthreads();                           // A tile + norms + mins visible

  for (int c = 0; c < 8; ++c) {
    f32x4 acc[4][2];
#pragma unroll
    for (int i = 0; i < 4; ++i)
#pragma unroll
      for (int j = 0; j < 2; ++j) acc[i][j] = (f32x4){0.f, 0.f, 0.f, 0.f};

    const unsigned short* Bc = Bl + (size_t)c * 128 * 256;
#pragma unroll
    for (int kk = 0; kk < 4; ++kk) {
      short8v b[2][2];
#pragma unroll
      for (int s = 0; s < 2; ++s)
#pragma unroll
        for (int j = 0; j < 2; ++j)
          b[s][j] = *(const short8v*)(Bc + j * 4096 + kk * 64 + s * 32);
#pragma unroll
      for (int s = 0; s < 2; ++s) {
        short8v a[4];
        int ph = (s * 4 + quad) ^ (l15 & 7);
#pragma unroll
        for (int i = 0; i < 4; ++i) {
          int ra = wr * 64 + i * 16 + l15;
          a[i] = *(const short8v*)&Ash[kk * 8192 + ra * 64 + ph * 8];
        }
#pragma unroll
        for (int i = 0; i < 4; ++i)
#pragma unroll
          for (int j = 0; j < 2; ++j)
            acc[i][j] = __builtin_amdgcn_mfma_f32_16x16x32_bf16(a[i], b[s][j], acc[i][j], 0, 0, 0);
      }
    }

    // chunk epilogue part 1: per-row min over this wave's 32 codes
#pragma unroll
    for (int i = 0; i < 4; ++i) {
#pragma unroll
      for (int reg = 0; reg < 4; ++reg) {
        int rl = wr * 64 + i * 16 + quad * 4 + reg;
        float an = an_s[rl];
        float bd = 3.402823466e+38f;
#pragma unroll
        for (int j = 0; j < 2; ++j) {
          int cl = wc * 32 + j * 16 + l15;
          float d = __fadd_rn(__fadd_rn(an, -2.0f * acc[i][j][reg]), cn_all[c * 128 + cl]);
          bd = (d < bd) ? d : bd;
        }
#pragma unroll
        for (int m = 1; m <= 8; m <<= 1) {
          float od = __shfl_xor(bd, m, 64);
          bd = (od < bd) ? od : bd;
        }
        if (l15 == 0) atomicMin(&rowmin[rl], __float_as_uint(bd));
      }
    }
    __syncthreads();                     // running min (incl. this chunk) visible
    // part 2: threshold append (rowmin monotone -> any later reads only tighten)
#pragma unroll
    for (int i = 0; i < 4; ++i) {
#pragma unroll
      for (int reg = 0; reg < 4; ++reg) {
        int rl = wr * 64 + i * 16 + quad * 4 + reg;
        float an = an_s[rl];
        float thr = __uint_as_float(rowmin[rl]) + MARGIN;
#pragma unroll
        for (int j = 0; j < 2; ++j) {
          int cl = wc * 32 + j * 16 + l15;
          float d = __fadd_rn(__fadd_rn(an, -2.0f * acc[i][j][reg]), cn_all[c * 128 + cl]);
          if (d <= thr) {
            unsigned int p = atomicAdd(lcnt, 1u);
            if (p < LCAP)
              lcand[p] = make_uint2(__float_as_uint(d),
                                    ((unsigned)rl << 10) | (unsigned)(c * 128 + cl));
          }
        }
      }
    }
  }
  __syncthreads();

  // ---- exact recheck (in-LDS) ----
  const float* cbq = cb + (size_t)q * KN * DN;
  const float* cnq = ws + WS_CNORM + q * KN;
  unsigned int n = *lcnt;
  if (n <= LCAP) {
    for (unsigned int e = tid; e < n; e += 512u) {
      uint2 en = lcand[e];
      int rl = en.y >> 10, code = en.y & 1023;
      float thr = __uint_as_float(rowmin[rl]) + MARGIN;
      if (__uint_as_float(en.x) > thr) continue;
      const float* r = rsrc + (size_t)(row0 + rl) * DN;
      const float* cc = cbq + (size_t)code * DN;
      float B = 0.f;
#pragma unroll 16
      for (int d = 0; d < DN; ++d) B = fmaf(r[d], cc[d], B);   // exact serial chain
      float de = __fadd_rn(__fadd_rn(an_s[rl], -2.0f * B), cnq[code]);
      unsigned long long key = ((unsigned long long)__float_as_uint(de) << 32) | (unsigned)code;
      atomicMin(&chc[rl], key);
    }
  } else {
    // safety fallback: exhaustive exact argmin (correct; expected never at LCAP=8192)
    for (int e = tid; e < 128 * 1024; e += 512) {
      int rl = e >> 10, code = e & 1023;
      const float* r = rsrc + (size_t)(row0 + rl) * DN;
      const float* cc = cbq + (size_t)code * DN;
      float B = 0.f;
#pragma unroll 16
      for (int d = 0; d < DN; ++d) B = fmaf(r[d], cc[d], B);
      float de = __fadd_rn(__fadd_rn(an_s[rl], -2.0f * B), cnq[code]);
      unsigned long long key = ((unsigned long long)__float_as_uint(de) << 32) | (unsigned)code;
      atomicMin(&chc[rl], key);
    }
  }
  __syncthreads();

  // ---- np-exact update: 4 passes x 32 rows, 16 thr/row x 16 dims, no barriers ----
  const bool last = (q == QN - 1);
  const int ur = tid >> 4, ud = tid & 15;                // ur in 0..31
  float lp = 0.f;
  for (int pass = 0; pass < 4; ++pass) {
    int rl = pass * 32 + ur;
    int row = row0 + rl;
    int idx = (int)(chc[rl] & 1023u);
    if (ud == 0) out[IDX_BASE + (size_t)q * NROWS + row] = (float)idx;

    const float4* r4 = (const float4*)(rsrc + (size_t)row * DN) + ud * 4;
    const float4* q4 = (const float4*)(cb + ((size_t)q * KN + idx) * DN) + ud * 4;
    float4 rnb[4];
#pragma unroll
    for (int t = 0; t < 4; ++t) {
      float4 r = r4[t], qv = q4[t];
      float tx = __fadd_rn(qv.x, -r.x), ty = __fadd_rn(qv.y, -r.y);
      float tz = __fadd_rn(qv.z, -r.z), tw = __fadd_rn(qv.w, -r.w);
      float sx = __fadd_rn(r.x, tx), sy = __fadd_rn(r.y, ty);
      float sz = __fadd_rn(r.z, tz), sw = __fadd_rn(r.w, tw);
      rnb[t] = make_float4(__fadd_rn(r.x, -sx), __fadd_rn(r.y, -sy),
                           __fadd_rn(r.z, -sz), __fadd_rn(r.w, -sw));
      lp = fmaf(tx, tx, lp); lp = fmaf(ty, ty, lp);
      lp = fmaf(tz, tz, lp); lp = fmaf(tw, tw, lp);
    }

    if (last) {
      const float4* z4 = (const float4*)(z + (size_t)row * DN) + ud * 4;
      float4* o4 = (float4*)(out + (size_t)row * DN) + ud * 4;
#pragma unroll
      for (int t = 0; t < 4; ++t) {
        float4 zv = z4[t];
        o4[t] = make_float4(__fadd_rn(zv.x, -rnb[t].x), __fadd_rn(zv.y, -rnb[t].y),
                            __fadd_rn(zv.z, -rnb[t].z), __fadd_rn(zv.w, -rnb[t].w));
      }
    } else {
      float4* rd = (float4*)(ws + WS_RESID + (size_t)row * DN) + ud * 4;
      ushort4* rs = (ushort4*)((unsigned short*)(ws + WS_RSPLIT) + (size_t)row * DN) + ud * 4;
#pragma unroll
      for (int t = 0; t < 4; ++t) {
        float4 v = rnb[t];
        rd[t] = v;
        rs[t] = make_ushort4(f2bf(v.x), f2bf(v.y), f2bf(v.z), f2bf(v.w));
      }
    }
  }

  if (!last) {
    __syncthreads();                        // RESID stores visible block-wide
    if (tid < 128)
      ws[WS_ANORM + row0 + tid] =
          sum256_sq_np(ws + WS_RESID + (size_t)(row0 + tid) * DN);  // same values as lr path
  }

#pragma unroll
  for (int off = 32; off > 0; off >>= 1) lp += __shfl_down(lp, off, 64);
  if (lane == 0) atomicAdd(ws + WS_LOSS + q, lp);
}

__global__ void rvq_fin(const float* __restrict__ ws, float* __restrict__ out) {
  if (blockIdx.x == 0 && threadIdx.x == 0) {
    float vq = 0.f;
    for (int q = 0; q < QN; ++q) {
      float m = ws[WS_LOSS + q] / 8388608.0f;
      float l = __fadd_rn(m, 0.25f * m);
      vq = __fadd_rn(vq, l);
    }
    out[LOSS_OFF] = vq;
  }
}

extern "C" void kernel_launch(void* const* d_in, const int* in_sizes, int n_in,
                              void* d_out, int out_size, void* d_ws, size_t ws_size,
                              hipStream_t stream) {
  const float* z = (const float*)d_in[0];
  const float* cb = (const float*)d_in[1];
  float* out = (float*)d_out;
  float* ws = (float*)d_ws;

  hipLaunchKernelGGL(rvq_prep_norm, dim3(32), dim3(256), 0, stream, cb, ws);
  hipLaunchKernelGGL(rvq_prep_cast, dim3(512), dim3(256), 0, stream, cb,
                     (unsigned short*)(ws + WS_CSPLIT));
  hipLaunchKernelGGL(rvq_init_rows, dim3(128), dim3(256), 0, stream, z, ws);

  for (int q = 0; q < QN; ++q)
    hipLaunchKernelGGL(rvq_fused, dim3(256), dim3(512), SM_BYTES, stream, z, cb, ws, out, q);

  hipLaunchKernelGGL(rvq_fin, dim3(1), dim3(64), 0, stream, ws, out);
}

// Round 4
// 942.601 us; speedup vs baseline: 1.5481x; 1.3300x over previous
//
#include <hip/hip_runtime.h>

#define QN 8
#define KN 1024
#define DN 256
#define NROWS 32768
#define IDX_BASE 8388608
#define LOSS_OFF 8650752
#define MARGIN 5e-3f
#define LCAP 8192u

// ws layout (float offsets)
#define WS_LOSS 0
#define WS_CNORM 8
#define WS_ANORM 8200        // unused now (an_s lives in LDS); kept for layout stability
#define WS_RESID 40968       // float[8388608]
#define WS_RSPLIT 8429576    // unused now; kept for layout stability
#define WS_CSPLIT 12623880   // bf16[2097152], fragment-major layout (see prep_cast)

// dynamic LDS layout (bytes)
#define SM_AFULL 0           // 65536: A row-tile 128x256 bf16, 4 swizzled kk-slices
#define SM_CN    65536       // 4096: all 1024 codebook norms for current q
#define SM_LCAND 69632       // 65536: uint2[8192]
#define SM_CHC   135168      // 1024
#define SM_ANS   136192      // 512
#define SM_RMIN  136704      // 512
#define SM_LCNT  137216      // 16
#define SM_BYTES 137232

typedef __attribute__((ext_vector_type(8))) short short8v;
typedef __attribute__((ext_vector_type(4))) float f32x4;

static __device__ __forceinline__ unsigned short f2bf(float x) {
  unsigned int u = __float_as_uint(x);
  unsigned int r = (u + 0x7fffu + ((u >> 16) & 1u)) >> 16;
  return (unsigned short)r;
}

// numpy pairwise sum-of-squares over 256 floats (validated: absmax 0.0)
__device__ __forceinline__ float sum256_sq_np(const float* p) {
  float h[2];
#pragma unroll
  for (int half = 0; half < 2; ++half) {
    const float* a = p + half * 128;
    float r[8];
#pragma unroll
    for (int j = 0; j < 8; ++j) r[j] = __fmul_rn(a[j], a[j]);
    for (int i = 8; i < 128; i += 8) {
#pragma unroll
      for (int j = 0; j < 8; ++j) r[j] = __fadd_rn(r[j], __fmul_rn(a[i + j], a[i + j]));
    }
    h[half] = __fadd_rn(__fadd_rn(__fadd_rn(r[0], r[1]), __fadd_rn(r[2], r[3])),
                        __fadd_rn(__fadd_rn(r[4], r[5]), __fadd_rn(r[6], r[7])));
  }
  return __fadd_rn(h[0], h[1]);
}

__global__ void rvq_prep_norm(const float* __restrict__ cb, float* __restrict__ ws) {
  int g = blockIdx.x * blockDim.x + threadIdx.x;
  if (g < 8) ws[WS_LOSS + g] = 0.f;
  if (g < QN * KN) ws[WS_CNORM + g] = sum256_sq_np(cb + (size_t)g * DN);
}

// Fragment-major bf16 codebook: 16B chunk index (per q) =
//   c*4096 + wc*1024 + kk*256 + s*128 + j*64 + lane
// holding code (wc*32 + j*16 + (lane&15)), dims [kk*64 + s*32 + (lane>>4)*8, +8).
// Screen b-loads become 64-lane contiguous 1KB transactions (was a 16-line gather).
__global__ void rvq_prep_cast(const float* __restrict__ cb, unsigned short* __restrict__ cs) {
  int gid = blockIdx.x * blockDim.x + threadIdx.x;
  uint4* s4 = (uint4*)cs;
#pragma unroll
  for (int k = 0; k < 2; ++k) {
    int ci = gid + k * 131072;               // 262144 chunks total
    int q = ci >> 15, rem = ci & 32767;
    int lane = rem & 63, fid = rem >> 6;
    int j = fid & 1, s = (fid >> 1) & 1, kk = (fid >> 2) & 3, wc = (fid >> 4) & 3, c = fid >> 6;
    int code = wc * 32 + j * 16 + (lane & 15);
    int doff = kk * 64 + s * 32 + (lane >> 4) * 8;
    const float4* src = (const float4*)(cb + ((size_t)(q * 1024 + c * 128 + code) * 256 + doff));
    float4 v0 = src[0], v1 = src[1];
    uint4 w;
    w.x = (unsigned)f2bf(v0.x) | ((unsigned)f2bf(v0.y) << 16);
    w.y = (unsigned)f2bf(v0.z) | ((unsigned)f2bf(v0.w) << 16);
    w.z = (unsigned)f2bf(v1.x) | ((unsigned)f2bf(v1.y) << 16);
    w.w = (unsigned)f2bf(v1.z) | ((unsigned)f2bf(v1.w) << 16);
    s4[ci] = w;
  }
}

// Single fused kernel over all 8 quantizers. Rows are block-private, so the
// q-loop needs only __syncthreads between stages. A-tile (bf16 residual) lives
// in LDS across q: update writes it directly (RSPLIT HBM round-trip removed).
// an_s maintained in LDS via the same np-exact sum256_sq_np on f32 RESID.
// Screen/recheck/update numerics identical to the validated R3 kernel.
__global__ __launch_bounds__(512, 2) void rvq_fused_all(const float* __restrict__ z,
                                                        const float* __restrict__ cb,
                                                        float* __restrict__ ws,
                                                        float* __restrict__ out) {
  extern __shared__ __align__(16) char smem[];
  uint4* Afull = (uint4*)(smem + SM_AFULL);            // 4096 uint4
  float* cn_all = (float*)(smem + SM_CN);              // 1024 norms
  uint2* lcand = (uint2*)(smem + SM_LCAND);
  unsigned long long* chc = (unsigned long long*)(smem + SM_CHC);
  float* an_s = (float*)(smem + SM_ANS);
  unsigned int* rowmin = (unsigned int*)(smem + SM_RMIN);
  unsigned int* lcnt = (unsigned int*)(smem + SM_LCNT);
  const unsigned short* Ash = (const unsigned short*)Afull;

  const int tid = threadIdx.x;
  const int row0 = blockIdx.x * 128;
  const int wv = tid >> 6, lane = tid & 63, quad = lane >> 4, l15 = lane & 15;
  const int wr = wv >> 2, wc = wv & 3;
  const int rb = tid >> 3, cch = tid & 7;

  // ---- q=0 init: ANORM(z) np-exact + A-tile = bf16(z) staged swizzled ----
  if (tid < 128) an_s[tid] = sum256_sq_np(z + (size_t)(row0 + tid) * DN);
#pragma unroll
  for (int kk2 = 0; kk2 < 4; ++kk2) {
#pragma unroll
    for (int p = 0; p < 2; ++p) {
      int r = p * 64 + rb;
      const float4* zp = (const float4*)(z + (size_t)(row0 + r) * DN + (kk2 * 8 + cch) * 8);
      float4 v0 = zp[0], v1 = zp[1];
      uint4 w;
      w.x = (unsigned)f2bf(v0.x) | ((unsigned)f2bf(v0.y) << 16);
      w.y = (unsigned)f2bf(v0.z) | ((unsigned)f2bf(v0.w) << 16);
      w.z = (unsigned)f2bf(v1.x) | ((unsigned)f2bf(v1.y) << 16);
      w.w = (unsigned)f2bf(v1.z) | ((unsigned)f2bf(v1.w) << 16);
      Afull[kk2 * 1024 + r * 8 + (cch ^ (r & 7))] = w;
    }
  }

  const uint4* Bf = (const uint4*)((const unsigned short*)(ws + WS_CSPLIT));

#pragma unroll 1
  for (int q = 0; q < QN; ++q) {
    const float* rsrc = (q == 0) ? z : (ws + WS_RESID);
    const bool last = (q == QN - 1);

    __syncthreads();                         // prior-q consumers done; A/an_s visible
    if (tid < 128) {
      rowmin[tid] = 0x7f7fffffu;
      chc[tid] = ~0ull;
    }
    cn_all[tid] = ws[WS_CNORM + q * KN + tid];
    cn_all[tid + 512] = ws[WS_CNORM + q * KN + tid + 512];
    if (tid == 0) *lcnt = 0u;
    __syncthreads();                         // init visible

    // ---- screen: 8 chunks of 128 codes, B fragments contiguous from global ----
    const uint4* Bl = Bf + ((size_t)q * 32768 + wc * 1024 + lane);
    for (int c = 0; c < 8; ++c) {
      f32x4 acc[4][2];
#pragma unroll
      for (int i = 0; i < 4; ++i)
#pragma unroll
        for (int j = 0; j < 2; ++j) acc[i][j] = (f32x4){0.f, 0.f, 0.f, 0.f};

      const uint4* Bc = Bl + c * 4096;
#pragma unroll
      for (int kk = 0; kk < 4; ++kk) {
        uint4 braw[2][2];
#pragma unroll
        for (int s = 0; s < 2; ++s)
#pragma unroll
          for (int j = 0; j < 2; ++j)
            braw[s][j] = Bc[kk * 256 + s * 128 + j * 64];
#pragma unroll
        for (int s = 0; s < 2; ++s) {
          short8v a[4];
          int ph = (s * 4 + quad) ^ (l15 & 7);
#pragma unroll
          for (int i = 0; i < 4; ++i) {
            int ra = wr * 64 + i * 16 + l15;
            a[i] = *(const short8v*)&Ash[kk * 8192 + ra * 64 + ph * 8];
          }
#pragma unroll
          for (int i = 0; i < 4; ++i)
#pragma unroll
            for (int j = 0; j < 2; ++j)
              acc[i][j] = __builtin_amdgcn_mfma_f32_16x16x32_bf16(
                  a[i], *(const short8v*)&braw[s][j], acc[i][j], 0, 0, 0);
        }
      }

      // chunk epilogue part 1: per-row min over this wave's 32 codes
#pragma unroll
      for (int i = 0; i < 4; ++i) {
#pragma unroll
        for (int reg = 0; reg < 4; ++reg) {
          int rl = wr * 64 + i * 16 + quad * 4 + reg;
          float an = an_s[rl];
          float bd = 3.402823466e+38f;
#pragma unroll
          for (int j = 0; j < 2; ++j) {
            int cl = wc * 32 + j * 16 + l15;
            float d = __fadd_rn(__fadd_rn(an, -2.0f * acc[i][j][reg]), cn_all[c * 128 + cl]);
            bd = (d < bd) ? d : bd;
          }
#pragma unroll
          for (int m = 1; m <= 8; m <<= 1) {
            float od = __shfl_xor(bd, m, 64);
            bd = (od < bd) ? od : bd;
          }
          if (l15 == 0) atomicMin(&rowmin[rl], __float_as_uint(bd));
        }
      }
      __syncthreads();                     // running min (incl. this chunk) visible
      // part 2: threshold append (rowmin monotone -> later reads only tighten)
#pragma unroll
      for (int i = 0; i < 4; ++i) {
#pragma unroll
        for (int reg = 0; reg < 4; ++reg) {
          int rl = wr * 64 + i * 16 + quad * 4 + reg;
          float an = an_s[rl];
          float thr = __uint_as_float(rowmin[rl]) + MARGIN;
#pragma unroll
          for (int j = 0; j < 2; ++j) {
            int cl = wc * 32 + j * 16 + l15;
            float d = __fadd_rn(__fadd_rn(an, -2.0f * acc[i][j][reg]), cn_all[c * 128 + cl]);
            if (d <= thr) {
              unsigned int p = atomicAdd(lcnt, 1u);
              if (p < LCAP)
                lcand[p] = make_uint2(__float_as_uint(d),
                                      ((unsigned)rl << 10) | (unsigned)(c * 128 + cl));
            }
          }
        }
      }
    }
    __syncthreads();

    // ---- exact recheck (in-LDS) ----
    const float* cbq = cb + (size_t)q * KN * DN;
    const float* cnq = ws + WS_CNORM + q * KN;
    unsigned int n = *lcnt;
    if (n <= LCAP) {
      for (unsigned int e = tid; e < n; e += 512u) {
        uint2 en = lcand[e];
        int rl = en.y >> 10, code = en.y & 1023;
        float thr = __uint_as_float(rowmin[rl]) + MARGIN;
        if (__uint_as_float(en.x) > thr) continue;
        const float* r = rsrc + (size_t)(row0 + rl) * DN;
        const float* cc = cbq + (size_t)code * DN;
        float B = 0.f;
#pragma unroll 16
        for (int d = 0; d < DN; ++d) B = fmaf(r[d], cc[d], B);   // exact serial chain
        float de = __fadd_rn(__fadd_rn(an_s[rl], -2.0f * B), cnq[code]);
        unsigned long long key = ((unsigned long long)__float_as_uint(de) << 32) | (unsigned)code;
        atomicMin(&chc[rl], key);
      }
    } else {
      // safety fallback: exhaustive exact argmin (correct; expected never at LCAP=8192)
      for (int e = tid; e < 128 * 1024; e += 512) {
        int rl = e >> 10, code = e & 1023;
        const float* r = rsrc + (size_t)(row0 + rl) * DN;
        const float* cc = cbq + (size_t)code * DN;
        float B = 0.f;
#pragma unroll 16
        for (int d = 0; d < DN; ++d) B = fmaf(r[d], cc[d], B);
        float de = __fadd_rn(__fadd_rn(an_s[rl], -2.0f * B), cnq[code]);
        unsigned long long key = ((unsigned long long)__float_as_uint(de) << 32) | (unsigned)code;
        atomicMin(&chc[rl], key);
      }
    }
    __syncthreads();                        // chc final; Afull free to overwrite

    // ---- np-exact update: 4 passes x 32 rows, 16 thr/row x 16 dims ----
    // Writes RESID f32 (global) and, for q<7, the NEXT A-tile bf16 directly
    // into LDS (same f2bf values, same swizzled layout as the staging path).
    const int ur = tid >> 4, ud = tid & 15;
    float lp = 0.f;
    for (int pass = 0; pass < 4; ++pass) {
      int rl = pass * 32 + ur;
      int row = row0 + rl;
      int idx = (int)(chc[rl] & 1023u);
      if (ud == 0) out[IDX_BASE + (size_t)q * NROWS + row] = (float)idx;

      const float4* r4 = (const float4*)(rsrc + (size_t)row * DN) + ud * 4;
      const float4* q4 = (const float4*)(cb + ((size_t)q * KN + idx) * DN) + ud * 4;
      float4 rnb[4];
#pragma unroll
      for (int t = 0; t < 4; ++t) {
        float4 r = r4[t], qv = q4[t];
        float tx = __fadd_rn(qv.x, -r.x), ty = __fadd_rn(qv.y, -r.y);
        float tz = __fadd_rn(qv.z, -r.z), tw = __fadd_rn(qv.w, -r.w);
        float sx = __fadd_rn(r.x, tx), sy = __fadd_rn(r.y, ty);
        float sz = __fadd_rn(r.z, tz), sw = __fadd_rn(r.w, tw);
        rnb[t] = make_float4(__fadd_rn(r.x, -sx), __fadd_rn(r.y, -sy),
                             __fadd_rn(r.z, -sz), __fadd_rn(r.w, -sw));
        lp = fmaf(tx, tx, lp); lp = fmaf(ty, ty, lp);
        lp = fmaf(tz, tz, lp); lp = fmaf(tw, tw, lp);
      }

      if (last) {
        const float4* z4 = (const float4*)(z + (size_t)row * DN) + ud * 4;
        float4* o4 = (float4*)(out + (size_t)row * DN) + ud * 4;
#pragma unroll
        for (int t = 0; t < 4; ++t) {
          float4 zv = z4[t];
          o4[t] = make_float4(__fadd_rn(zv.x, -rnb[t].x), __fadd_rn(zv.y, -rnb[t].y),
                              __fadd_rn(zv.z, -rnb[t].z), __fadd_rn(zv.w, -rnb[t].w));
        }
      } else {
        float4* rd = (float4*)(ws + WS_RESID + (size_t)row * DN) + ud * 4;
#pragma unroll
        for (int t = 0; t < 4; ++t) rd[t] = rnb[t];
        // next A-tile bf16 into LDS: uint4 u0=2*ud (dims ud*16..+8), u1=u0+1 (+8..+16)
        uint4 w0, w1;
        w0.x = (unsigned)f2bf(rnb[0].x) | ((unsigned)f2bf(rnb[0].y) << 16);
        w0.y = (unsigned)f2bf(rnb[0].z) | ((unsigned)f2bf(rnb[0].w) << 16);
        w0.z = (unsigned)f2bf(rnb[1].x) | ((unsigned)f2bf(rnb[1].y) << 16);
        w0.w = (unsigned)f2bf(rnb[1].z) | ((unsigned)f2bf(rnb[1].w) << 16);
        w1.x = (unsigned)f2bf(rnb[2].x) | ((unsigned)f2bf(rnb[2].y) << 16);
        w1.y = (unsigned)f2bf(rnb[2].z) | ((unsigned)f2bf(rnb[2].w) << 16);
        w1.z = (unsigned)f2bf(rnb[3].x) | ((unsigned)f2bf(rnb[3].y) << 16);
        w1.w = (unsigned)f2bf(rnb[3].z) | ((unsigned)f2bf(rnb[3].w) << 16);
        int u0 = 2 * ud, u1 = u0 + 1;
        Afull[(u0 >> 3) * 1024 + rl * 8 + ((u0 & 7) ^ (rl & 7))] = w0;
        Afull[(u1 >> 3) * 1024 + rl * 8 + ((u1 & 7) ^ (rl & 7))] = w1;
      }
    }

#pragma unroll
    for (int off = 32; off > 0; off >>= 1) lp += __shfl_down(lp, off, 64);
    if (lane == 0) atomicAdd(ws + WS_LOSS + q, lp);

    if (!last) {
      __syncthreads();                      // RESID stores drained/visible
      if (tid < 128)
        an_s[tid] = sum256_sq_np(ws + WS_RESID + (size_t)(row0 + tid) * DN);
    }
  }
}

__global__ void rvq_fin(const float* __restrict__ ws, float* __restrict__ out) {
  if (blockIdx.x == 0 && threadIdx.x == 0) {
    float vq = 0.f;
    for (int q = 0; q < QN; ++q) {
      float m = ws[WS_LOSS + q] / 8388608.0f;
      float l = __fadd_rn(m, 0.25f * m);
      vq = __fadd_rn(vq, l);
    }
    out[LOSS_OFF] = vq;
  }
}

extern "C" void kernel_launch(void* const* d_in, const int* in_sizes, int n_in,
                              void* d_out, int out_size, void* d_ws, size_t ws_size,
                              hipStream_t stream) {
  const float* z = (const float*)d_in[0];
  const float* cb = (const float*)d_in[1];
  float* out = (float*)d_out;
  float* ws = (float*)d_ws;

  hipLaunchKernelGGL(rvq_prep_norm, dim3(32), dim3(256), 0, stream, cb, ws);
  hipLaunchKernelGGL(rvq_prep_cast, dim3(512), dim3(256), 0, stream, cb,
                     (unsigned short*)(ws + WS_CSPLIT));
  hipLaunchKernelGGL(rvq_fused_all, dim3(256), dim3(512), SM_BYTES, stream, z, cb, ws, out);
  hipLaunchKernelGGL(rvq_fin, dim3(1), dim3(64), 0, stream, ws, out);
}

// Round 5
// 859.761 us; speedup vs baseline: 1.6973x; 1.0964x over previous
//
#include <hip/hip_runtime.h>

#define QN 8
#define KN 1024
#define DN 256
#define NROWS 32768
#define IDX_BASE 8388608
#define LOSS_OFF 8650752
#define MARGIN 5e-3f
#define LCAP 5888u

// ws layout (float offsets)
#define WS_LOSS 0
#define WS_CNORM 8
#define WS_CSPLIT 12623880   // bf16[2097152], fragment-major layout (see prep_cast)

// dynamic LDS layout (bytes). Residual f32 tile lives HERE for the whole
// kernel: no RESID global round-trip at all (was ~450 MB HBM + 3 latency
// chains per q).
#define SM_RES   0           // 133120: float[128][260] residual (256 data + 4 pad)
#define SM_LCAND 133120      // 23552: uint[5888] id-only candidates
#define SM_CN    156672      // 4096: all 1024 codebook norms for current q
#define SM_CHC   160768      // 1024
#define SM_ANS   161792      // 512
#define SM_RMIN  162304      // 512
#define SM_LCNT  162816      // 16
#define SM_BYTES 162832
#define RESW 260

typedef __attribute__((ext_vector_type(8))) short short8v;
typedef __attribute__((ext_vector_type(4))) float f32x4;

static __device__ __forceinline__ unsigned short f2bf(float x) {
  unsigned int u = __float_as_uint(x);
  unsigned int r = (u + 0x7fffu + ((u >> 16) & 1u)) >> 16;
  return (unsigned short)r;
}

// HW RNE f32->bf16 pair; bit-identical to f2bf for finite inputs.
static __device__ __forceinline__ unsigned cvt_pk_bf16(float lo, float hi) {
  unsigned r;
  asm("v_cvt_pk_bf16_f32 %0, %1, %2" : "=v"(r) : "v"(lo), "v"(hi));
  return r;
}

// numpy pairwise sum-of-squares over 256 floats (validated: absmax 0.0)
__device__ __forceinline__ float sum256_sq_np(const float* p) {
  float h[2];
#pragma unroll
  for (int half = 0; half < 2; ++half) {
    const float* a = p + half * 128;
    float r[8];
#pragma unroll
    for (int j = 0; j < 8; ++j) r[j] = __fmul_rn(a[j], a[j]);
    for (int i = 8; i < 128; i += 8) {
#pragma unroll
      for (int j = 0; j < 8; ++j) r[j] = __fadd_rn(r[j], __fmul_rn(a[i + j], a[i + j]));
    }
    h[half] = __fadd_rn(__fadd_rn(__fadd_rn(r[0], r[1]), __fadd_rn(r[2], r[3])),
                        __fadd_rn(__fadd_rn(r[4], r[5]), __fadd_rn(r[6], r[7])));
  }
  return __fadd_rn(h[0], h[1]);
}

__global__ void rvq_prep_norm(const float* __restrict__ cb, float* __restrict__ ws) {
  int g = blockIdx.x * blockDim.x + threadIdx.x;
  if (g < 8) ws[WS_LOSS + g] = 0.f;
  if (g < QN * KN) ws[WS_CNORM + g] = sum256_sq_np(cb + (size_t)g * DN);
}

// Fragment-major bf16 codebook: 16B chunk index (per q) =
//   c*4096 + wc*1024 + kk*256 + s*128 + j*64 + lane
// holding code (wc*32 + j*16 + (lane&15)), dims [kk*64 + s*32 + (lane>>4)*8, +8).
__global__ void rvq_prep_cast(const float* __restrict__ cb, unsigned short* __restrict__ cs) {
  int gid = blockIdx.x * blockDim.x + threadIdx.x;
  uint4* s4 = (uint4*)cs;
#pragma unroll
  for (int k = 0; k < 2; ++k) {
    int ci = gid + k * 131072;               // 262144 chunks total
    int q = ci >> 15, rem = ci & 32767;
    int lane = rem & 63, fid = rem >> 6;
    int j = fid & 1, s = (fid >> 1) & 1, kk = (fid >> 2) & 3, wc = (fid >> 4) & 3, c = fid >> 6;
    int code = wc * 32 + j * 16 + (lane & 15);
    int doff = kk * 64 + s * 32 + (lane >> 4) * 8;
    const float4* src = (const float4*)(cb + ((size_t)(q * 1024 + c * 128 + code) * 256 + doff));
    float4 v0 = src[0], v1 = src[1];
    uint4 w;
    w.x = (unsigned)f2bf(v0.x) | ((unsigned)f2bf(v0.y) << 16);
    w.y = (unsigned)f2bf(v0.z) | ((unsigned)f2bf(v0.w) << 16);
    w.z = (unsigned)f2bf(v1.x) | ((unsigned)f2bf(v1.y) << 16);
    w.w = (unsigned)f2bf(v1.z) | ((unsigned)f2bf(v1.w) << 16);
    s4[ci] = w;
  }
}

// Single fused kernel, all 8 quantizers, residual tile LDS-resident.
// Per q: a-fragments converted once (RNE) into registers; screen MFMA order,
// epilogue, serial-fmaf recheck, u64 tie-break, np-exact update all
// bit-identical to the validated R4 kernel.
__global__ __launch_bounds__(512, 2) void rvq_fused_all(const float* __restrict__ z,
                                                        const float* __restrict__ cb,
                                                        float* __restrict__ ws,
                                                        float* __restrict__ out) {
  extern __shared__ __align__(16) char smem[];
  float* RES = (float*)(smem + SM_RES);                // [128][260]
  unsigned int* lcand = (unsigned int*)(smem + SM_LCAND);
  float* cn_all = (float*)(smem + SM_CN);              // 1024 norms
  unsigned long long* chc = (unsigned long long*)(smem + SM_CHC);
  float* an_s = (float*)(smem + SM_ANS);
  unsigned int* rowmin = (unsigned int*)(smem + SM_RMIN);
  unsigned int* lcnt = (unsigned int*)(smem + SM_LCNT);

  const int tid = threadIdx.x;
  const int row0 = blockIdx.x * 128;
  const int wv = tid >> 6, lane = tid & 63, quad = lane >> 4, l15 = lane & 15;
  const int wr = wv >> 2, wc = wv & 3;

  // ---- init: copy z tile -> LDS RES (f32 exact), then ANORM(z) np-exact ----
  const float4* zb = (const float4*)(z + (size_t)row0 * DN);
#pragma unroll
  for (int k = 0; k < 16; ++k) {
    int fi = k * 512 + tid;                  // float4 index in 128x256 tile
    int rr = fi >> 6, dd = (fi & 63) * 4;
    *(float4*)&RES[rr * RESW + dd] = zb[fi];
  }
  __syncthreads();
  if (tid < 128) an_s[tid] = sum256_sq_np(&RES[tid * RESW]);

  const uint4* Bf = (const uint4*)((const unsigned short*)(ws + WS_CSPLIT));

#pragma unroll 1
  for (int q = 0; q < QN; ++q) {
    const bool last = (q == QN - 1);

    __syncthreads();                         // RES/an_s stable; prior-q consumers done
    if (tid < 128) {
      rowmin[tid] = 0x7f7fffffu;
      chc[tid] = ~0ull;
    }
    cn_all[tid] = ws[WS_CNORM + q * KN + tid];
    cn_all[tid + 512] = ws[WS_CNORM + q * KN + tid + 512];
    if (tid == 0) *lcnt = 0u;

    // a-fragments: read f32 from LDS once, cvt RNE -> bf16 regs (32 frags)
    short8v areg[4][2][4];                   // [i][s][kk]
#pragma unroll
    for (int kk = 0; kk < 4; ++kk) {
#pragma unroll
      for (int s = 0; s < 2; ++s) {
#pragma unroll
        for (int i = 0; i < 4; ++i) {
          int ra = wr * 64 + i * 16 + l15;
          int g = kk * 8 + s * 4 + quad;     // 8-dim group: dims g*8..g*8+8
          const float* fp = &RES[ra * RESW + g * 8];
          float4 v0 = *(const float4*)fp;
          float4 v1 = *(const float4*)(fp + 4);
          uint4 w;
          w.x = cvt_pk_bf16(v0.x, v0.y);
          w.y = cvt_pk_bf16(v0.z, v0.w);
          w.z = cvt_pk_bf16(v1.x, v1.y);
          w.w = cvt_pk_bf16(v1.z, v1.w);
          areg[i][s][kk] = *(short8v*)&w;
        }
      }
    }
    __syncthreads();                         // init visible

    // ---- screen: 8 chunks of 128 codes, B fragments contiguous from global ----
    const uint4* Bl = Bf + ((size_t)q * 32768 + wc * 1024 + lane);
    for (int c = 0; c < 8; ++c) {
      f32x4 acc[4][2];
#pragma unroll
      for (int i = 0; i < 4; ++i)
#pragma unroll
        for (int j = 0; j < 2; ++j) acc[i][j] = (f32x4){0.f, 0.f, 0.f, 0.f};

      const uint4* Bc = Bl + c * 4096;
#pragma unroll
      for (int kk = 0; kk < 4; ++kk) {
        uint4 braw[2][2];
#pragma unroll
        for (int s = 0; s < 2; ++s)
#pragma unroll
          for (int j = 0; j < 2; ++j)
            braw[s][j] = Bc[kk * 256 + s * 128 + j * 64];
#pragma unroll
        for (int s = 0; s < 2; ++s)
#pragma unroll
          for (int i = 0; i < 4; ++i)
#pragma unroll
            for (int j = 0; j < 2; ++j)
              acc[i][j] = __builtin_amdgcn_mfma_f32_16x16x32_bf16(
                  areg[i][s][kk], *(const short8v*)&braw[s][j], acc[i][j], 0, 0, 0);
      }

      // chunk epilogue part 1: per-row min over this wave's 32 codes
#pragma unroll
      for (int i = 0; i < 4; ++i) {
#pragma unroll
        for (int reg = 0; reg < 4; ++reg) {
          int rl = wr * 64 + i * 16 + quad * 4 + reg;
          float an = an_s[rl];
          float bd = 3.402823466e+38f;
#pragma unroll
          for (int j = 0; j < 2; ++j) {
            int cl = wc * 32 + j * 16 + l15;
            float d = __fadd_rn(__fadd_rn(an, -2.0f * acc[i][j][reg]), cn_all[c * 128 + cl]);
            bd = (d < bd) ? d : bd;
          }
#pragma unroll
          for (int m = 1; m <= 8; m <<= 1) {
            float od = __shfl_xor(bd, m, 64);
            bd = (od < bd) ? od : bd;
          }
          if (l15 == 0) atomicMin(&rowmin[rl], __float_as_uint(bd));
        }
      }
      __syncthreads();                     // running min (incl. this chunk) visible
      // part 2: threshold append (rowmin monotone -> later reads only tighten)
#pragma unroll
      for (int i = 0; i < 4; ++i) {
#pragma unroll
        for (int reg = 0; reg < 4; ++reg) {
          int rl = wr * 64 + i * 16 + quad * 4 + reg;
          float an = an_s[rl];
          float thr = __uint_as_float(rowmin[rl]) + MARGIN;
#pragma unroll
          for (int j = 0; j < 2; ++j) {
            int cl = wc * 32 + j * 16 + l15;
            float d = __fadd_rn(__fadd_rn(an, -2.0f * acc[i][j][reg]), cn_all[c * 128 + cl]);
            if (d <= thr) {
              unsigned int p = atomicAdd(lcnt, 1u);
              if (p < LCAP)
                lcand[p] = ((unsigned)rl << 10) | (unsigned)(c * 128 + cl);
            }
          }
        }
      }
    }
    __syncthreads();

    // ---- exact recheck: residual rows from LDS, codebook f32 from global ----
    const float* cbq = cb + (size_t)q * KN * DN;
    const float* cnq = ws + WS_CNORM + q * KN;
    unsigned int n = *lcnt;
    if (n <= LCAP) {
      for (unsigned int e = tid; e < n; e += 512u) {
        unsigned int en = lcand[e];
        int rl = en >> 10, code = en & 1023;
        const float* r = &RES[rl * RESW];
        const float* cc = cbq + (size_t)code * DN;
        float B = 0.f;
#pragma unroll 16
        for (int d = 0; d < DN; ++d) B = fmaf(r[d], cc[d], B);   // exact serial chain
        float de = __fadd_rn(__fadd_rn(an_s[rl], -2.0f * B), cnq[code]);
        unsigned long long key = ((unsigned long long)__float_as_uint(de) << 32) | (unsigned)code;
        atomicMin(&chc[rl], key);
      }
    } else {
      // safety fallback: exhaustive exact argmin (correct; expected never)
      for (int e = tid; e < 128 * 1024; e += 512) {
        int rl = e >> 10, code = e & 1023;
        const float* r = &RES[rl * RESW];
        const float* cc = cbq + (size_t)code * DN;
        float B = 0.f;
#pragma unroll 16
        for (int d = 0; d < DN; ++d) B = fmaf(r[d], cc[d], B);
        float de = __fadd_rn(__fadd_rn(an_s[rl], -2.0f * B), cnq[code]);
        unsigned long long key = ((unsigned long long)__float_as_uint(de) << 32) | (unsigned)code;
        atomicMin(&chc[rl], key);
      }
    }
    __syncthreads();                        // chc final

    // ---- np-exact update in LDS: 4 passes x 32 rows, 16 thr/row x 16 dims ----
    const int ur = tid >> 4, ud = tid & 15;
    float lp = 0.f;
    for (int pass = 0; pass < 4; ++pass) {
      int rl = pass * 32 + ur;
      int row = row0 + rl;
      int idx = (int)(chc[rl] & 1023u);
      if (ud == 0) out[IDX_BASE + (size_t)q * NROWS + row] = (float)idx;

      float4* r4 = (float4*)&RES[rl * RESW + ud * 16];
      const float4* q4 = (const float4*)(cb + ((size_t)q * KN + idx) * DN) + ud * 4;
      float4 rnb[4];
#pragma unroll
      for (int t = 0; t < 4; ++t) {
        float4 r = r4[t], qv = q4[t];
        float tx = __fadd_rn(qv.x, -r.x), ty = __fadd_rn(qv.y, -r.y);
        float tz = __fadd_rn(qv.z, -r.z), tw = __fadd_rn(qv.w, -r.w);
        float sx = __fadd_rn(r.x, tx), sy = __fadd_rn(r.y, ty);
        float sz = __fadd_rn(r.z, tz), sw = __fadd_rn(r.w, tw);
        rnb[t] = make_float4(__fadd_rn(r.x, -sx), __fadd_rn(r.y, -sy),
                             __fadd_rn(r.z, -sz), __fadd_rn(r.w, -sw));
        lp = fmaf(tx, tx, lp); lp = fmaf(ty, ty, lp);
        lp = fmaf(tz, tz, lp); lp = fmaf(tw, tw, lp);
      }

      if (last) {
        const float4* z4 = (const float4*)(z + (size_t)row * DN) + ud * 4;
        float4* o4 = (float4*)(out + (size_t)row * DN) + ud * 4;
#pragma unroll
        for (int t = 0; t < 4; ++t) {
          float4 zv = z4[t];
          o4[t] = make_float4(__fadd_rn(zv.x, -rnb[t].x), __fadd_rn(zv.y, -rnb[t].y),
                              __fadd_rn(zv.z, -rnb[t].z), __fadd_rn(zv.w, -rnb[t].w));
        }
      } else {
#pragma unroll
        for (int t = 0; t < 4; ++t) r4[t] = rnb[t];   // residual stays in LDS
      }
    }

#pragma unroll
    for (int off = 32; off > 0; off >>= 1) lp += __shfl_down(lp, off, 64);
    if (lane == 0) atomicAdd(ws + WS_LOSS + q, lp);

    if (!last) {
      __syncthreads();                      // RES updates visible
      if (tid < 128) an_s[tid] = sum256_sq_np(&RES[tid * RESW]);
    }
  }
}

__global__ void rvq_fin(const float* __restrict__ ws, float* __restrict__ out) {
  if (blockIdx.x == 0 && threadIdx.x == 0) {
    float vq = 0.f;
    for (int q = 0; q < QN; ++q) {
      float m = ws[WS_LOSS + q] / 8388608.0f;
      float l = __fadd_rn(m, 0.25f * m);
      vq = __fadd_rn(vq, l);
    }
    out[LOSS_OFF] = vq;
  }
}

extern "C" void kernel_launch(void* const* d_in, const int* in_sizes, int n_in,
                              void* d_out, int out_size, void* d_ws, size_t ws_size,
                              hipStream_t stream) {
  const float* z = (const float*)d_in[0];
  const float* cb = (const float*)d_in[1];
  float* out = (float*)d_out;
  float* ws = (float*)d_ws;

  hipLaunchKernelGGL(rvq_prep_norm, dim3(32), dim3(256), 0, stream, cb, ws);
  hipLaunchKernelGGL(rvq_prep_cast, dim3(512), dim3(256), 0, stream, cb,
                     (unsigned short*)(ws + WS_CSPLIT));
  hipLaunchKernelGGL(rvq_fused_all, dim3(256), dim3(512), SM_BYTES, stream, z, cb, ws, out);
  hipLaunchKernelGGL(rvq_fin, dim3(1), dim3(64), 0, stream, ws, out);
}

// Round 6
// 794.095 us; speedup vs baseline: 1.8376x; 1.0827x over previous
//
#include <hip/hip_runtime.h>

#define QN 8
#define KN 1024
#define DN 256
#define NROWS 32768
#define IDX_BASE 8388608
#define LOSS_OFF 8650752
#define MARGIN 5e-3f
#define LCAP 3072u

// ws layout (float offsets)
#define WS_LOSS 0
#define WS_CNORM 8
#define WS_CSPLIT 12623880   // bf16[2097152], fragment-major layout (see prep_cast)

// dynamic LDS layout (bytes). 78 KB -> 2 independent blocks/CU so one block's
// phase bubbles (barrier drains, phase-boundary latency) overlap the other's
// compute. Residual f32 tile stays LDS-resident (R5 win, kept).
#define SM_RES   0           // 66560: float[64][260] residual (256 data + 4 pad)
#define SM_LCAND 66560       // 12288: uint[3072] id-only candidates
#define SM_CHC   78848       // 512
#define SM_ANS   79360       // 256
#define SM_RMIN  79616       // 256
#define SM_LCNT  79872       // 16
#define SM_BYTES 79888
#define RESW 260

typedef __attribute__((ext_vector_type(8))) short short8v;
typedef __attribute__((ext_vector_type(4))) float f32x4;

static __device__ __forceinline__ unsigned short f2bf(float x) {
  unsigned int u = __float_as_uint(x);
  unsigned int r = (u + 0x7fffu + ((u >> 16) & 1u)) >> 16;
  return (unsigned short)r;
}

// HW RNE f32->bf16 pair; bit-identical to f2bf for finite inputs.
static __device__ __forceinline__ unsigned cvt_pk_bf16(float lo, float hi) {
  unsigned r;
  asm("v_cvt_pk_bf16_f32 %0, %1, %2" : "=v"(r) : "v"(lo), "v"(hi));
  return r;
}

// numpy pairwise sum-of-squares over 256 floats (validated: absmax 0.0)
__device__ __forceinline__ float sum256_sq_np(const float* p) {
  float h[2];
#pragma unroll
  for (int half = 0; half < 2; ++half) {
    const float* a = p + half * 128;
    float r[8];
#pragma unroll
    for (int j = 0; j < 8; ++j) r[j] = __fmul_rn(a[j], a[j]);
    for (int i = 8; i < 128; i += 8) {
#pragma unroll
      for (int j = 0; j < 8; ++j) r[j] = __fadd_rn(r[j], __fmul_rn(a[i + j], a[i + j]));
    }
    h[half] = __fadd_rn(__fadd_rn(__fadd_rn(r[0], r[1]), __fadd_rn(r[2], r[3])),
                        __fadd_rn(__fadd_rn(r[4], r[5]), __fadd_rn(r[6], r[7])));
  }
  return __fadd_rn(h[0], h[1]);
}

__global__ void rvq_prep_norm(const float* __restrict__ cb, float* __restrict__ ws) {
  int g = blockIdx.x * blockDim.x + threadIdx.x;
  if (g < 8) ws[WS_LOSS + g] = 0.f;
  if (g < QN * KN) ws[WS_CNORM + g] = sum256_sq_np(cb + (size_t)g * DN);
}

// Fragment-major bf16 codebook: 16B chunk index (per q) =
//   c*4096 + wc2*1024 + kk*256 + s*128 + j2*64 + lane
// holding code (wc2*32 + j2*16 + (lane&15)), dims [kk*64 + s*32 + (lane>>4)*8, +8).
__global__ void rvq_prep_cast(const float* __restrict__ cb, unsigned short* __restrict__ cs) {
  int gid = blockIdx.x * blockDim.x + threadIdx.x;
  uint4* s4 = (uint4*)cs;
#pragma unroll
  for (int k = 0; k < 2; ++k) {
    int ci = gid + k * 131072;               // 262144 chunks total
    int q = ci >> 15, rem = ci & 32767;
    int lane = rem & 63, fid = rem >> 6;
    int j = fid & 1, s = (fid >> 1) & 1, kk = (fid >> 2) & 3, wc = (fid >> 4) & 3, c = fid >> 6;
    int code = wc * 32 + j * 16 + (lane & 15);
    int doff = kk * 64 + s * 32 + (lane >> 4) * 8;
    const float4* src = (const float4*)(cb + ((size_t)(q * 1024 + c * 128 + code) * 256 + doff));
    float4 v0 = src[0], v1 = src[1];
    uint4 w;
    w.x = (unsigned)f2bf(v0.x) | ((unsigned)f2bf(v0.y) << 16);
    w.y = (unsigned)f2bf(v0.z) | ((unsigned)f2bf(v0.w) << 16);
    w.z = (unsigned)f2bf(v1.x) | ((unsigned)f2bf(v1.y) << 16);
    w.w = (unsigned)f2bf(v1.z) | ((unsigned)f2bf(v1.w) << 16);
    s4[ci] = w;
  }
}

// Single fused kernel, all 8 quantizers. 64-row tile, 256 threads (4 waves,
// wr 2 x wc 2), 78 KB LDS -> 2 blocks/CU. A-fragments: 16 per wave, converted
// RNE once per q into registers (64 VGPR; no spill, unlike R5's 32-frag/128).
// Screen MFMA order (kk-major, s-minor per acc), epilogue expression tree,
// margin, serial-fmaf recheck, u64 tie-break, np-exact update: bit-identical
// to the validated R5 kernel.
__global__ __launch_bounds__(256, 2) void rvq_fused_all(const float* __restrict__ z,
                                                        const float* __restrict__ cb,
                                                        float* __restrict__ ws,
                                                        float* __restrict__ out) {
  extern __shared__ __align__(16) char smem[];
  float* RES = (float*)(smem + SM_RES);                // [64][260]
  unsigned int* lcand = (unsigned int*)(smem + SM_LCAND);
  unsigned long long* chc = (unsigned long long*)(smem + SM_CHC);
  float* an_s = (float*)(smem + SM_ANS);
  unsigned int* rowmin = (unsigned int*)(smem + SM_RMIN);
  unsigned int* lcnt = (unsigned int*)(smem + SM_LCNT);

  const int tid = threadIdx.x;
  const int row0 = blockIdx.x * 64;
  const int wv = tid >> 6, lane = tid & 63, quad = lane >> 4, l15 = lane & 15;
  const int wr = wv >> 1, wc = wv & 1;

  // ---- init: copy z tile -> LDS RES (f32 exact), then ANORM(z) np-exact ----
  const float4* zb = (const float4*)(z + (size_t)row0 * DN);
#pragma unroll
  for (int k = 0; k < 16; ++k) {
    int fi = k * 256 + tid;                  // float4 index in 64x256 tile
    int rr = fi >> 6, dd = (fi & 63) * 4;
    *(float4*)&RES[rr * RESW + dd] = zb[fi];
  }
  __syncthreads();
  if (tid < 64) an_s[tid] = sum256_sq_np(&RES[tid * RESW]);

  const uint4* Bf = (const uint4*)((const unsigned short*)(ws + WS_CSPLIT));

#pragma unroll 1
  for (int q = 0; q < QN; ++q) {
    const bool last = (q == QN - 1);

    __syncthreads();                         // RES/an_s stable; prior-q consumers done
    if (tid < 64) {
      rowmin[tid] = 0x7f7fffffu;
      chc[tid] = ~0ull;
    }
    if (tid == 0) *lcnt = 0u;

    // a-fragments: read f32 from LDS once per q, cvt RNE -> bf16 regs (16 frags)
    short8v areg[2][2][4];                   // [i][s][kk] = 64 VGPR
#pragma unroll
    for (int kk = 0; kk < 4; ++kk) {
#pragma unroll
      for (int s = 0; s < 2; ++s) {
#pragma unroll
        for (int i = 0; i < 2; ++i) {
          int ra = wr * 32 + i * 16 + l15;
          int g = kk * 8 + s * 4 + quad;     // 8-dim group: dims g*8..g*8+8
          const float* fp = &RES[ra * RESW + g * 8];
          float4 v0 = *(const float4*)fp;
          float4 v1 = *(const float4*)(fp + 4);
          uint4 w;
          w.x = cvt_pk_bf16(v0.x, v0.y);
          w.y = cvt_pk_bf16(v0.z, v0.w);
          w.z = cvt_pk_bf16(v1.x, v1.y);
          w.w = cvt_pk_bf16(v1.z, v1.w);
          areg[i][s][kk] = *(short8v*)&w;
        }
      }
    }
    __syncthreads();                         // init visible

    // ---- screen: 8 chunks of 128 codes; B contiguous from global (L2) ----
    const uint4* Bl = Bf + ((size_t)q * 32768 + lane);
    const float* cnq_g = ws + WS_CNORM + q * KN;
    for (int c = 0; c < 8; ++c) {
      float cnr[4];                          // L1-hot scalar norms, hidden under MFMA
#pragma unroll
      for (int j = 0; j < 4; ++j) cnr[j] = cnq_g[c * 128 + wc * 64 + j * 16 + l15];

      f32x4 acc[2][4];
#pragma unroll
      for (int i = 0; i < 2; ++i)
#pragma unroll
        for (int j = 0; j < 4; ++j) acc[i][j] = (f32x4){0.f, 0.f, 0.f, 0.f};

      const uint4* Bc = Bl + c * 4096;
#pragma unroll
      for (int kk = 0; kk < 4; ++kk) {
        uint4 braw[2][4];
#pragma unroll
        for (int s = 0; s < 2; ++s)
#pragma unroll
          for (int j = 0; j < 4; ++j)
            braw[s][j] = Bc[(wc * 2 + (j >> 1)) * 1024 + kk * 256 + s * 128 + (j & 1) * 64];
#pragma unroll
        for (int s = 0; s < 2; ++s)
#pragma unroll
          for (int i = 0; i < 2; ++i)
#pragma unroll
            for (int j = 0; j < 4; ++j)
              acc[i][j] = __builtin_amdgcn_mfma_f32_16x16x32_bf16(
                  areg[i][s][kk], *(const short8v*)&braw[s][j], acc[i][j], 0, 0, 0);
      }

      // chunk epilogue part 1: per-row min over this wave's 64 codes
#pragma unroll
      for (int i = 0; i < 2; ++i) {
#pragma unroll
        for (int reg = 0; reg < 4; ++reg) {
          int rl = wr * 32 + i * 16 + quad * 4 + reg;
          float an = an_s[rl];
          float bd = 3.402823466e+38f;
#pragma unroll
          for (int j = 0; j < 4; ++j) {
            float d = __fadd_rn(__fadd_rn(an, -2.0f * acc[i][j][reg]), cnr[j]);
            bd = (d < bd) ? d : bd;
          }
#pragma unroll
          for (int m = 1; m <= 8; m <<= 1) {
            float od = __shfl_xor(bd, m, 64);
            bd = (od < bd) ? od : bd;
          }
          if (l15 == 0) atomicMin(&rowmin[rl], __float_as_uint(bd));
        }
      }
      __syncthreads();                     // running min (incl. this chunk) visible
      // part 2: threshold append (rowmin monotone -> later reads only tighten)
#pragma unroll
      for (int i = 0; i < 2; ++i) {
#pragma unroll
        for (int reg = 0; reg < 4; ++reg) {
          int rl = wr * 32 + i * 16 + quad * 4 + reg;
          float an = an_s[rl];
          float thr = __uint_as_float(rowmin[rl]) + MARGIN;
#pragma unroll
          for (int j = 0; j < 4; ++j) {
            float d = __fadd_rn(__fadd_rn(an, -2.0f * acc[i][j][reg]), cnr[j]);
            if (d <= thr) {
              unsigned int p = atomicAdd(lcnt, 1u);
              if (p < LCAP)
                lcand[p] = ((unsigned)rl << 10) |
                           (unsigned)(c * 128 + wc * 64 + j * 16 + l15);
            }
          }
        }
      }
    }
    __syncthreads();

    // ---- exact recheck: residual rows from LDS, codebook f32 from global ----
    const float* cbq = cb + (size_t)q * KN * DN;
    const float* cnq = ws + WS_CNORM + q * KN;
    unsigned int n = *lcnt;
    if (n <= LCAP) {
      for (unsigned int e = tid; e < n; e += 256u) {
        unsigned int en = lcand[e];
        int rl = en >> 10, code = en & 1023;
        const float* r = &RES[rl * RESW];
        const float* cc = cbq + (size_t)code * DN;
        float B = 0.f;
#pragma unroll 16
        for (int d = 0; d < DN; ++d) B = fmaf(r[d], cc[d], B);   // exact serial chain
        float de = __fadd_rn(__fadd_rn(an_s[rl], -2.0f * B), cnq[code]);
        unsigned long long key = ((unsigned long long)__float_as_uint(de) << 32) | (unsigned)code;
        atomicMin(&chc[rl], key);
      }
    } else {
      // safety fallback: exhaustive exact argmin (correct; expected never)
      for (int e = tid; e < 64 * 1024; e += 256) {
        int rl = e >> 10, code = e & 1023;
        const float* r = &RES[rl * RESW];
        const float* cc = cbq + (size_t)code * DN;
        float B = 0.f;
#pragma unroll 16
        for (int d = 0; d < DN; ++d) B = fmaf(r[d], cc[d], B);
        float de = __fadd_rn(__fadd_rn(an_s[rl], -2.0f * B), cnq[code]);
        unsigned long long key = ((unsigned long long)__float_as_uint(de) << 32) | (unsigned)code;
        atomicMin(&chc[rl], key);
      }
    }
    __syncthreads();                        // chc final

    // ---- np-exact update in LDS: 4 passes x 16 rows, 16 thr/row x 16 dims ----
    const int ur = tid >> 4, ud = tid & 15;  // ur in 0..15
    float lp = 0.f;
    for (int pass = 0; pass < 4; ++pass) {
      int rl = pass * 16 + ur;
      int row = row0 + rl;
      int idx = (int)(chc[rl] & 1023u);
      if (ud == 0) out[IDX_BASE + (size_t)q * NROWS + row] = (float)idx;

      float4* r4 = (float4*)&RES[rl * RESW + ud * 16];
      const float4* q4 = (const float4*)(cb + ((size_t)q * KN + idx) * DN) + ud * 4;
      float4 rnb[4];
#pragma unroll
      for (int t = 0; t < 4; ++t) {
        float4 r = r4[t], qv = q4[t];
        float tx = __fadd_rn(qv.x, -r.x), ty = __fadd_rn(qv.y, -r.y);
        float tz = __fadd_rn(qv.z, -r.z), tw = __fadd_rn(qv.w, -r.w);
        float sx = __fadd_rn(r.x, tx), sy = __fadd_rn(r.y, ty);
        float sz = __fadd_rn(r.z, tz), sw = __fadd_rn(r.w, tw);
        rnb[t] = make_float4(__fadd_rn(r.x, -sx), __fadd_rn(r.y, -sy),
                             __fadd_rn(r.z, -sz), __fadd_rn(r.w, -sw));
        lp = fmaf(tx, tx, lp); lp = fmaf(ty, ty, lp);
        lp = fmaf(tz, tz, lp); lp = fmaf(tw, tw, lp);
      }

      if (last) {
        const float4* z4 = (const float4*)(z + (size_t)row * DN) + ud * 4;
        float4* o4 = (float4*)(out + (size_t)row * DN) + ud * 4;
#pragma unroll
        for (int t = 0; t < 4; ++t) {
          float4 zv = z4[t];
          o4[t] = make_float4(__fadd_rn(zv.x, -rnb[t].x), __fadd_rn(zv.y, -rnb[t].y),
                              __fadd_rn(zv.z, -rnb[t].z), __fadd_rn(zv.w, -rnb[t].w));
        }
      } else {
#pragma unroll
        for (int t = 0; t < 4; ++t) r4[t] = rnb[t];   // residual stays in LDS
      }
    }

#pragma unroll
    for (int off = 32; off > 0; off >>= 1) lp += __shfl_down(lp, off, 64);
    if (lane == 0) atomicAdd(ws + WS_LOSS + q, lp);

    if (!last) {
      __syncthreads();                      // RES updates visible
      if (tid < 64) an_s[tid] = sum256_sq_np(&RES[tid * RESW]);
    }
  }
}

__global__ void rvq_fin(const float* __restrict__ ws, float* __restrict__ out) {
  if (blockIdx.x == 0 && threadIdx.x == 0) {
    float vq = 0.f;
    for (int q = 0; q < QN; ++q) {
      float m = ws[WS_LOSS + q] / 8388608.0f;
      float l = __fadd_rn(m, 0.25f * m);
      vq = __fadd_rn(vq, l);
    }
    out[LOSS_OFF] = vq;
  }
}

extern "C" void kernel_launch(void* const* d_in, const int* in_sizes, int n_in,
                              void* d_out, int out_size, void* d_ws, size_t ws_size,
                              hipStream_t stream) {
  const float* z = (const float*)d_in[0];
  const float* cb = (const float*)d_in[1];
  float* out = (float*)d_out;
  float* ws = (float*)d_ws;

  hipLaunchKernelGGL(rvq_prep_norm, dim3(32), dim3(256), 0, stream, cb, ws);
  hipLaunchKernelGGL(rvq_prep_cast, dim3(512), dim3(256), 0, stream, cb,
                     (unsigned short*)(ws + WS_CSPLIT));
  hipLaunchKernelGGL(rvq_fused_all, dim3(512), dim3(256), SM_BYTES, stream, z, cb, ws, out);
  hipLaunchKernelGGL(rvq_fin, dim3(1), dim3(64), 0, stream, ws, out);
}

// Round 7
// 719.145 us; speedup vs baseline: 2.0291x; 1.1042x over previous
//
#include <hip/hip_runtime.h>

#define QN 8
#define KN 1024
#define DN 256
#define NROWS 32768
#define IDX_BASE 8388608
#define LOSS_OFF 8650752
#define MARGIN 5e-3f
#define LCAP 3072u

// ws layout (float offsets)
#define WS_LOSS 0
#define WS_CNORM 8
#define WS_CSPLIT 12623880   // bf16[2097152], fragment-major layout (see prep_cast)

// dynamic LDS layout (bytes). 78 KB -> 2 blocks/CU; with 512 threads/block
// that is 16 waves/CU = 4 waves/SIMD (was 2) for latency hiding.
#define SM_RES   0           // 66560: float[64][260] residual (256 data + 4 pad)
#define SM_LCAND 66560       // 12288: uint[3072] id-only candidates
#define SM_CHC   78848       // 512
#define SM_ANS   79360       // 256
#define SM_RMIN  79616       // 256
#define SM_LCNT  79872       // 16 (lcnt @ +0, lsum @ +4)
#define SM_BYTES 79888
#define RESW 260

typedef __attribute__((ext_vector_type(8))) short short8v;
typedef __attribute__((ext_vector_type(4))) float f32x4;

static __device__ __forceinline__ unsigned short f2bf(float x) {
  unsigned int u = __float_as_uint(x);
  unsigned int r = (u + 0x7fffu + ((u >> 16) & 1u)) >> 16;
  return (unsigned short)r;
}

// HW RNE f32->bf16 pair; bit-identical to f2bf for finite inputs.
static __device__ __forceinline__ unsigned cvt_pk_bf16(float lo, float hi) {
  unsigned r;
  asm("v_cvt_pk_bf16_f32 %0, %1, %2" : "=v"(r) : "v"(lo), "v"(hi));
  return r;
}

// numpy pairwise sum-of-squares over 256 floats (validated: absmax 0.0)
__device__ __forceinline__ float sum256_sq_np(const float* p) {
  float h[2];
#pragma unroll
  for (int half = 0; half < 2; ++half) {
    const float* a = p + half * 128;
    float r[8];
#pragma unroll
    for (int j = 0; j < 8; ++j) r[j] = __fmul_rn(a[j], a[j]);
    for (int i = 8; i < 128; i += 8) {
#pragma unroll
      for (int j = 0; j < 8; ++j) r[j] = __fadd_rn(r[j], __fmul_rn(a[i + j], a[i + j]));
    }
    h[half] = __fadd_rn(__fadd_rn(__fadd_rn(r[0], r[1]), __fadd_rn(r[2], r[3])),
                        __fadd_rn(__fadd_rn(r[4], r[5]), __fadd_rn(r[6], r[7])));
  }
  return __fadd_rn(h[0], h[1]);
}

__global__ void rvq_prep_norm(const float* __restrict__ cb, float* __restrict__ ws) {
  int g = blockIdx.x * blockDim.x + threadIdx.x;
  if (g < 8) ws[WS_LOSS + g] = 0.f;
  if (g < QN * KN) ws[WS_CNORM + g] = sum256_sq_np(cb + (size_t)g * DN);
}

// Fragment-major bf16 codebook: 16B chunk index (per q) =
//   c*4096 + wc*1024 + kk*256 + s*128 + j*64 + lane
// holding code (wc*32 + j*16 + (lane&15)), dims [kk*64 + s*32 + (lane>>4)*8, +8).
__global__ void rvq_prep_cast(const float* __restrict__ cb, unsigned short* __restrict__ cs) {
  int gid = blockIdx.x * blockDim.x + threadIdx.x;
  uint4* s4 = (uint4*)cs;
#pragma unroll
  for (int k = 0; k < 2; ++k) {
    int ci = gid + k * 131072;               // 262144 chunks total
    int q = ci >> 15, rem = ci & 32767;
    int lane = rem & 63, fid = rem >> 6;
    int j = fid & 1, s = (fid >> 1) & 1, kk = (fid >> 2) & 3, wc = (fid >> 4) & 3, c = fid >> 6;
    int code = wc * 32 + j * 16 + (lane & 15);
    int doff = kk * 64 + s * 32 + (lane >> 4) * 8;
    const float4* src = (const float4*)(cb + ((size_t)(q * 1024 + c * 128 + code) * 256 + doff));
    float4 v0 = src[0], v1 = src[1];
    uint4 w;
    w.x = (unsigned)f2bf(v0.x) | ((unsigned)f2bf(v0.y) << 16);
    w.y = (unsigned)f2bf(v0.z) | ((unsigned)f2bf(v0.w) << 16);
    w.z = (unsigned)f2bf(v1.x) | ((unsigned)f2bf(v1.y) << 16);
    w.w = (unsigned)f2bf(v1.z) | ((unsigned)f2bf(v1.w) << 16);
    s4[ci] = w;
  }
}

// Single fused kernel, all 8 quantizers. 64-row tile, 512 threads = 8 waves
// (wr 2 x wc 4), 78 KB LDS -> 2 blocks/CU -> 4 waves/SIMD (R6 had 2: every
// dependent-latency event was exposed). Screen is now barrier-free: merged
// epilogue uses thr = min(racy rowmin, own chunk-min) + MARGIN, a superset of
// the old post-barrier candidate set; exact recheck unchanged => identical
// argmins. 5 barriers/q (was ~21). Screen d expression, MFMA (kk,s) order per
// acc, margin, serial-fmaf recheck, u64 tie-break, np-exact update: all
// bit-identical to the validated R6 kernel.
__global__ __launch_bounds__(512, 4) void rvq_fused_all(const float* __restrict__ z,
                                                        const float* __restrict__ cb,
                                                        float* __restrict__ ws,
                                                        float* __restrict__ out) {
  extern __shared__ __align__(16) char smem[];
  float* RES = (float*)(smem + SM_RES);                // [64][260]
  unsigned int* lcand = (unsigned int*)(smem + SM_LCAND);
  unsigned long long* chc = (unsigned long long*)(smem + SM_CHC);
  float* an_s = (float*)(smem + SM_ANS);
  unsigned int* rowmin = (unsigned int*)(smem + SM_RMIN);
  unsigned int* lcnt = (unsigned int*)(smem + SM_LCNT);
  float* lsum = (float*)(smem + SM_LCNT + 4);

  const int tid = threadIdx.x;
  const int row0 = blockIdx.x * 64;
  const int wv = tid >> 6, lane = tid & 63, quad = lane >> 4, l15 = lane & 15;
  const int wr = wv >> 2, wc = wv & 3;

  // ---- init: copy z tile -> LDS RES (f32 exact), then ANORM(z) np-exact ----
  const float4* zb = (const float4*)(z + (size_t)row0 * DN);
#pragma unroll
  for (int k = 0; k < 8; ++k) {
    int fi = k * 512 + tid;                  // float4 index in 64x256 tile
    int rr = fi >> 6, dd = (fi & 63) * 4;
    *(float4*)&RES[rr * RESW + dd] = zb[fi];
  }
  if (tid == 0) *lsum = 0.f;
  __syncthreads();
  if (tid < 64) an_s[tid] = sum256_sq_np(&RES[tid * RESW]);

  const uint4* Bf = (const uint4*)((const unsigned short*)(ws + WS_CSPLIT));

#pragma unroll 1
  for (int q = 0; q < QN; ++q) {
    const bool last = (q == QN - 1);

    __syncthreads();                         // RES/an_s stable; prior-q consumers done
    if (tid < 64) {
      rowmin[tid] = 0x7f7fffffu;
      chc[tid] = ~0ull;
    }
    if (tid == 0) *lcnt = 0u;

    // a-fragments: read f32 from LDS once per q, cvt RNE -> bf16 regs (16 frags)
    short8v areg[2][2][4];                   // [i][s][kk] = 64 VGPR
#pragma unroll
    for (int kk = 0; kk < 4; ++kk) {
#pragma unroll
      for (int s = 0; s < 2; ++s) {
#pragma unroll
        for (int i = 0; i < 2; ++i) {
          int ra = wr * 32 + i * 16 + l15;
          int g = kk * 8 + s * 4 + quad;     // 8-dim group: dims g*8..g*8+8
          const float* fp = &RES[ra * RESW + g * 8];
          float4 v0 = *(const float4*)fp;
          float4 v1 = *(const float4*)(fp + 4);
          uint4 w;
          w.x = cvt_pk_bf16(v0.x, v0.y);
          w.y = cvt_pk_bf16(v0.z, v0.w);
          w.z = cvt_pk_bf16(v1.x, v1.y);
          w.w = cvt_pk_bf16(v1.z, v1.w);
          areg[i][s][kk] = *(short8v*)&w;
        }
      }
    }
    __syncthreads();                         // resets visible; screen may start

    // ---- screen: 8 chunks of 128 codes, barrier-free ----
    const uint4* Bl = Bf + ((size_t)q * 32768 + wc * 1024 + lane);
    const float* cnq_g = ws + WS_CNORM + q * KN;
    for (int c = 0; c < 8; ++c) {
      float cnr[2];                          // L1-hot scalar norms
#pragma unroll
      for (int j = 0; j < 2; ++j) cnr[j] = cnq_g[c * 128 + wc * 32 + j * 16 + l15];

      f32x4 acc[2][2];
#pragma unroll
      for (int i = 0; i < 2; ++i)
#pragma unroll
        for (int j = 0; j < 2; ++j) acc[i][j] = (f32x4){0.f, 0.f, 0.f, 0.f};

      const uint4* Bc = Bl + c * 4096;
#pragma unroll
      for (int kk = 0; kk < 4; ++kk) {
        uint4 braw[2][2];
#pragma unroll
        for (int s = 0; s < 2; ++s)
#pragma unroll
          for (int j = 0; j < 2; ++j)
            braw[s][j] = Bc[kk * 256 + s * 128 + j * 64];
#pragma unroll
        for (int s = 0; s < 2; ++s)
#pragma unroll
          for (int i = 0; i < 2; ++i)
#pragma unroll
            for (int j = 0; j < 2; ++j)
              acc[i][j] = __builtin_amdgcn_mfma_f32_16x16x32_bf16(
                  areg[i][s][kk], *(const short8v*)&braw[s][j], acc[i][j], 0, 0, 0);
      }

      // merged epilogue: per-row wave-min, racy-safe threshold, append.
      // thr = min(rowmin_read, own chunk wave-min) + MARGIN >= final thr
      // -> candidate superset; exact recheck resolves identically.
#pragma unroll
      for (int i = 0; i < 2; ++i) {
#pragma unroll
        for (int reg = 0; reg < 4; ++reg) {
          int rl = wr * 32 + i * 16 + quad * 4 + reg;
          float an = an_s[rl];
          float d0 = __fadd_rn(__fadd_rn(an, -2.0f * acc[i][0][reg]), cnr[0]);
          float d1 = __fadd_rn(__fadd_rn(an, -2.0f * acc[i][1][reg]), cnr[1]);
          float bd = 3.402823466e+38f;
          bd = (d0 < bd) ? d0 : bd;
          bd = (d1 < bd) ? d1 : bd;
#pragma unroll
          for (int m = 1; m <= 8; m <<= 1) {
            float od = __shfl_xor(bd, m, 64);
            bd = (od < bd) ? od : bd;
          }
          float rmf = __uint_as_float(rowmin[rl]);     // racy read: only tightens
          if (l15 == 0) atomicMin(&rowmin[rl], __float_as_uint(bd));
          float tb = (bd < rmf) ? bd : rmf;
          float thr = tb + MARGIN;
          if (d0 <= thr) {
            unsigned int p = atomicAdd(lcnt, 1u);
            if (p < LCAP)
              lcand[p] = ((unsigned)rl << 10) | (unsigned)(c * 128 + wc * 32 + l15);
          }
          if (d1 <= thr) {
            unsigned int p = atomicAdd(lcnt, 1u);
            if (p < LCAP)
              lcand[p] = ((unsigned)rl << 10) | (unsigned)(c * 128 + wc * 32 + 16 + l15);
          }
        }
      }
    }
    __syncthreads();                         // appends + final rowmin + lcnt visible

    // ---- exact recheck: residual rows from LDS, codebook f32 from global ----
    const float* cbq = cb + (size_t)q * KN * DN;
    const float* cnq = ws + WS_CNORM + q * KN;
    unsigned int n = *lcnt;
    if (n <= LCAP) {
      for (unsigned int e = tid; e < n; e += 512u) {
        unsigned int en = lcand[e];
        int rl = en >> 10, code = en & 1023;
        const float* r = &RES[rl * RESW];
        const float* cc = cbq + (size_t)code * DN;
        float B = 0.f;
#pragma unroll 16
        for (int d = 0; d < DN; ++d) B = fmaf(r[d], cc[d], B);   // exact serial chain
        float de = __fadd_rn(__fadd_rn(an_s[rl], -2.0f * B), cnq[code]);
        unsigned long long key = ((unsigned long long)__float_as_uint(de) << 32) | (unsigned)code;
        atomicMin(&chc[rl], key);
      }
    } else {
      // safety fallback: exhaustive exact argmin (correct; expected never)
      for (int e = tid; e < 64 * 1024; e += 512) {
        int rl = e >> 10, code = e & 1023;
        const float* r = &RES[rl * RESW];
        const float* cc = cbq + (size_t)code * DN;
        float B = 0.f;
#pragma unroll 16
        for (int d = 0; d < DN; ++d) B = fmaf(r[d], cc[d], B);
        float de = __fadd_rn(__fadd_rn(an_s[rl], -2.0f * B), cnq[code]);
        unsigned long long key = ((unsigned long long)__float_as_uint(de) << 32) | (unsigned)code;
        atomicMin(&chc[rl], key);
      }
    }
    __syncthreads();                        // chc final

    // ---- np-exact update in LDS: 2 passes x 32 rows, 16 thr/row x 16 dims ----
    const int ur = tid >> 4, ud = tid & 15;  // ur in 0..31
    float lp = 0.f;
    for (int pass = 0; pass < 2; ++pass) {
      int rl = pass * 32 + ur;
      int row = row0 + rl;
      int idx = (int)(chc[rl] & 1023u);
      if (ud == 0) out[IDX_BASE + (size_t)q * NROWS + row] = (float)idx;

      float4* r4 = (float4*)&RES[rl * RESW + ud * 16];
      const float4* q4 = (const float4*)(cb + ((size_t)q * KN + idx) * DN) + ud * 4;
      float4 rnb[4];
#pragma unroll
      for (int t = 0; t < 4; ++t) {
        float4 r = r4[t], qv = q4[t];
        float tx = __fadd_rn(qv.x, -r.x), ty = __fadd_rn(qv.y, -r.y);
        float tz = __fadd_rn(qv.z, -r.z), tw = __fadd_rn(qv.w, -r.w);
        float sx = __fadd_rn(r.x, tx), sy = __fadd_rn(r.y, ty);
        float sz = __fadd_rn(r.z, tz), sw = __fadd_rn(r.w, tw);
        rnb[t] = make_float4(__fadd_rn(r.x, -sx), __fadd_rn(r.y, -sy),
                             __fadd_rn(r.z, -sz), __fadd_rn(r.w, -sw));
        lp = fmaf(tx, tx, lp); lp = fmaf(ty, ty, lp);
        lp = fmaf(tz, tz, lp); lp = fmaf(tw, tw, lp);
      }

      if (last) {
        const float4* z4 = (const float4*)(z + (size_t)row * DN) + ud * 4;
        float4* o4 = (float4*)(out + (size_t)row * DN) + ud * 4;
#pragma unroll
        for (int t = 0; t < 4; ++t) {
          float4 zv = z4[t];
          o4[t] = make_float4(__fadd_rn(zv.x, -rnb[t].x), __fadd_rn(zv.y, -rnb[t].y),
                              __fadd_rn(zv.z, -rnb[t].z), __fadd_rn(zv.w, -rnb[t].w));
        }
      } else {
#pragma unroll
        for (int t = 0; t < 4; ++t) r4[t] = rnb[t];   // residual stays in LDS
      }
    }

#pragma unroll
    for (int off = 32; off > 0; off >>= 1) lp += __shfl_down(lp, off, 64);
    if (lane == 0) atomicAdd(lsum, lp);     // LDS f32 add: 8 wave partials

    __syncthreads();                        // RES updates + lsum complete
    if (!last && tid < 64) an_s[tid] = sum256_sq_np(&RES[tid * RESW]);
    if (tid == 0) {                         // one global atomic per block per q
      atomicAdd(ws + WS_LOSS + q, *lsum);
      *lsum = 0.f;
    }
  }
}

__global__ void rvq_fin(const float* __restrict__ ws, float* __restrict__ out) {
  if (blockIdx.x == 0 && threadIdx.x == 0) {
    float vq = 0.f;
    for (int q = 0; q < QN; ++q) {
      float m = ws[WS_LOSS + q] / 8388608.0f;
      float l = __fadd_rn(m, 0.25f * m);
      vq = __fadd_rn(vq, l);
    }
    out[LOSS_OFF] = vq;
  }
}

extern "C" void kernel_launch(void* const* d_in, const int* in_sizes, int n_in,
                              void* d_out, int out_size, void* d_ws, size_t ws_size,
                              hipStream_t stream) {
  const float* z = (const float*)d_in[0];
  const float* cb = (const float*)d_in[1];
  float* out = (float*)d_out;
  float* ws = (float*)d_ws;

  hipLaunchKernelGGL(rvq_prep_norm, dim3(32), dim3(256), 0, stream, cb, ws);
  hipLaunchKernelGGL(rvq_prep_cast, dim3(512), dim3(256), 0, stream, cb,
                     (unsigned short*)(ws + WS_CSPLIT));
  hipLaunchKernelGGL(rvq_fused_all, dim3(512), dim3(512), SM_BYTES, stream, z, cb, ws, out);
  hipLaunchKernelGGL(rvq_fin, dim3(1), dim3(64), 0, stream, ws, out);
}